// Round 1
// baseline (4725.453 us; speedup 1.0000x reference)
//
#include <hip/hip_runtime.h>
#include <hip/hip_bf16.h>
#include <cstddef>

// Problem constants (from reference)
#define B_    16
#define T_    1024
#define C_    1024
#define K_    8
#define H_    1536
#define TNEI_ 2
static constexpr float EPS_ = 1e-5f;

// ---------------------------------------------------------------------------
// Tiled fp32 GEMM: C[M,N] = A[M,K] @ B[K,N] (+bias) (+relu)
// 128x128 tile, BK=16, 256 threads, 8x8 micro-tile per thread.
// All dims divisible by tile sizes for this problem (M=16384, N/K in {1024,1536}).
// ---------------------------------------------------------------------------
template <int BIAS, int RELU>
__global__ __launch_bounds__(256) void sgemm_kernel(
    const float* __restrict__ A, const float* __restrict__ Bm,
    const float* __restrict__ bias, float* __restrict__ Cm,
    int M, int N, int Kd)
{
    constexpr int BM = 128, BN = 128, BK = 16, PAD = 4;
    __shared__ float As[BK][BM + PAD];
    __shared__ float Bs[BK][BN + PAD];

    const int tid = threadIdx.x;
    const int tx = tid & 15;        // 0..15 -> N direction
    const int ty = tid >> 4;        // 0..15 -> M direction
    const int row0 = blockIdx.y * BM;
    const int col0 = blockIdx.x * BN;

    float acc[8][8] = {};

    for (int k0 = 0; k0 < Kd; k0 += BK) {
        // Load A tile (128 rows x 16 cols), 512 float4 by 256 threads.
        #pragma unroll
        for (int it = 0; it < 2; ++it) {
            const int idx = tid + it * 256;
            const int r  = idx >> 2;          // 0..127
            const int c4 = (idx & 3) * 4;     // 0,4,8,12
            const float4 v = *reinterpret_cast<const float4*>(
                &A[(size_t)(row0 + r) * Kd + k0 + c4]);
            As[c4 + 0][r] = v.x;
            As[c4 + 1][r] = v.y;
            As[c4 + 2][r] = v.z;
            As[c4 + 3][r] = v.w;
        }
        // Load B tile (16 rows x 128 cols), 512 float4 by 256 threads.
        #pragma unroll
        for (int it = 0; it < 2; ++it) {
            const int idx = tid + it * 256;
            const int r  = idx >> 5;          // 0..15
            const int c4 = (idx & 31) * 4;    // 0..124
            const float4 v = *reinterpret_cast<const float4*>(
                &Bm[(size_t)(k0 + r) * N + col0 + c4]);
            *reinterpret_cast<float4*>(&Bs[r][c4]) = v;
        }
        __syncthreads();

        #pragma unroll
        for (int k = 0; k < BK; ++k) {
            float a[8], b[8];
            const float4 a0 = *reinterpret_cast<const float4*>(&As[k][ty * 8]);
            const float4 a1 = *reinterpret_cast<const float4*>(&As[k][ty * 8 + 4]);
            const float4 b0 = *reinterpret_cast<const float4*>(&Bs[k][tx * 8]);
            const float4 b1 = *reinterpret_cast<const float4*>(&Bs[k][tx * 8 + 4]);
            a[0]=a0.x; a[1]=a0.y; a[2]=a0.z; a[3]=a0.w;
            a[4]=a1.x; a[5]=a1.y; a[6]=a1.z; a[7]=a1.w;
            b[0]=b0.x; b[1]=b0.y; b[2]=b0.z; b[3]=b0.w;
            b[4]=b1.x; b[5]=b1.y; b[6]=b1.z; b[7]=b1.w;
            #pragma unroll
            for (int i = 0; i < 8; ++i)
                #pragma unroll
                for (int j = 0; j < 8; ++j)
                    acc[i][j] = fmaf(a[i], b[j], acc[i][j]);
        }
        __syncthreads();
    }

    // Epilogue
    #pragma unroll
    for (int i = 0; i < 8; ++i) {
        const int r = row0 + ty * 8 + i;
        #pragma unroll
        for (int j = 0; j < 8; j += 4) {
            const int c = col0 + tx * 8 + j;
            float4 v = make_float4(acc[i][j], acc[i][j+1], acc[i][j+2], acc[i][j+3]);
            if (BIAS) {
                v.x += bias[c + 0]; v.y += bias[c + 1];
                v.z += bias[c + 2]; v.w += bias[c + 3];
            }
            if (RELU) {
                v.x = fmaxf(v.x, 0.f); v.y = fmaxf(v.y, 0.f);
                v.z = fmaxf(v.z, 0.f); v.w = fmaxf(v.w, 0.f);
            }
            *reinterpret_cast<float4*>(&Cm[(size_t)r * N + c]) = v;
        }
    }
}

// ---------------------------------------------------------------------------
// Neighbor attention: one block per (b,t) row.
// scores[k] = dot(q[bt], kbuf[b, inxs[bt,k]]) * scale + radj[bt,k]
// out[bt]   = sum_k softmax(scores)[k] * vbuf[b, inxs[bt,k]]
// out may alias q (row-local read-then-write).
// ---------------------------------------------------------------------------
__global__ __launch_bounds__(256) void attn_kernel(
    const float* __restrict__ q, const float* __restrict__ kbuf,
    const float* __restrict__ vbuf, const int* __restrict__ inxs,
    const float* __restrict__ radj, float* __restrict__ out)
{
    const int bt  = blockIdx.x;          // 0 .. B*T-1
    const int b   = bt >> 10;            // T = 1024
    const int tid = threadIdx.x;
    const float scale = 0.03125f;        // 1/sqrt(1024)

    __shared__ int   s_idx[K_];
    __shared__ float s_sc[K_];
    __shared__ float red[K_][4];

    if (tid < K_) s_idx[tid] = inxs[bt * K_ + tid];
    __syncthreads();

    const float4 qv = *reinterpret_cast<const float4*>(&q[(size_t)bt * C_ + tid * 4]);

    float part[K_];
    #pragma unroll
    for (int k = 0; k < K_; ++k) {
        const size_t nb = (size_t)b * T_ + s_idx[k];
        const float4 kv = *reinterpret_cast<const float4*>(&kbuf[nb * C_ + tid * 4]);
        part[k] = qv.x * kv.x + qv.y * kv.y + qv.z * kv.z + qv.w * kv.w;
    }

    const int lane = tid & 63, wid = tid >> 6;
    #pragma unroll
    for (int k = 0; k < K_; ++k) {
        float v = part[k];
        #pragma unroll
        for (int off = 32; off; off >>= 1) v += __shfl_xor(v, off);
        if (lane == 0) red[k][wid] = v;
    }
    __syncthreads();
    if (tid < K_) {
        s_sc[tid] = (red[tid][0] + red[tid][1] + red[tid][2] + red[tid][3]) * scale
                    + radj[bt * K_ + tid];
    }
    __syncthreads();

    // softmax over 8, computed redundantly in every thread
    float m = s_sc[0];
    #pragma unroll
    for (int k = 1; k < K_; ++k) m = fmaxf(m, s_sc[k]);
    float w[K_], wsum = 0.f;
    #pragma unroll
    for (int k = 0; k < K_; ++k) { w[k] = expf(s_sc[k] - m); wsum += w[k]; }
    const float inv = 1.0f / wsum;

    float4 o = make_float4(0.f, 0.f, 0.f, 0.f);
    #pragma unroll
    for (int k = 0; k < K_; ++k) {
        const size_t nb = (size_t)b * T_ + s_idx[k];
        const float4 vv = *reinterpret_cast<const float4*>(&vbuf[nb * C_ + tid * 4]);
        const float wk = w[k] * inv;
        o.x = fmaf(wk, vv.x, o.x); o.y = fmaf(wk, vv.y, o.y);
        o.z = fmaf(wk, vv.z, o.z); o.w = fmaf(wk, vv.w, o.w);
    }
    *reinterpret_cast<float4*>(&out[(size_t)bt * C_ + tid * 4]) = o;
}

// ---------------------------------------------------------------------------
// out = LayerNorm(a + (RELU ? relu(b) : b)) * g + beta, row length C_=1024.
// One block (256 threads) per row, 4 floats per thread.
// ---------------------------------------------------------------------------
template <int RELU>
__global__ __launch_bounds__(256) void ln_residual_kernel(
    const float* __restrict__ a, const float* __restrict__ bb,
    const float* __restrict__ g, const float* __restrict__ beta,
    float* __restrict__ out)
{
    const int bt  = blockIdx.x;
    const int tid = threadIdx.x;

    const float4 av = *reinterpret_cast<const float4*>(&a[(size_t)bt * C_ + tid * 4]);
    const float4 bv = *reinterpret_cast<const float4*>(&bb[(size_t)bt * C_ + tid * 4]);
    float4 s;
    s.x = av.x + (RELU ? fmaxf(bv.x, 0.f) : bv.x);
    s.y = av.y + (RELU ? fmaxf(bv.y, 0.f) : bv.y);
    s.z = av.z + (RELU ? fmaxf(bv.z, 0.f) : bv.z);
    s.w = av.w + (RELU ? fmaxf(bv.w, 0.f) : bv.w);

    float sum = s.x + s.y + s.z + s.w;
    float sq  = s.x * s.x + s.y * s.y + s.z * s.z + s.w * s.w;

    const int lane = tid & 63, wid = tid >> 6;
    __shared__ float rs[4], rq[4];
    #pragma unroll
    for (int off = 32; off; off >>= 1) {
        sum += __shfl_xor(sum, off);
        sq  += __shfl_xor(sq,  off);
    }
    if (lane == 0) { rs[wid] = sum; rq[wid] = sq; }
    __syncthreads();
    sum = rs[0] + rs[1] + rs[2] + rs[3];
    sq  = rq[0] + rq[1] + rq[2] + rq[3];

    const float mu  = sum * (1.0f / C_);
    const float var = sq * (1.0f / C_) - mu * mu;
    const float r   = rsqrtf(var + EPS_);

    const float4 gv = *reinterpret_cast<const float4*>(&g[tid * 4]);
    const float4 be = *reinterpret_cast<const float4*>(&beta[tid * 4]);
    float4 o;
    o.x = (s.x - mu) * r * gv.x + be.x;
    o.y = (s.y - mu) * r * gv.y + be.y;
    o.z = (s.z - mu) * r * gv.z + be.z;
    o.w = (s.w - mu) * r * gv.w + be.w;
    *reinterpret_cast<float4*>(&out[(size_t)bt * C_ + tid * 4]) = o;
}

// ---------------------------------------------------------------------------
extern "C" void kernel_launch(void* const* d_in, const int* in_sizes, int n_in,
                              void* d_out, int out_size, void* d_ws, size_t ws_size,
                              hipStream_t stream)
{
    const float* x     = (const float*)d_in[0];
    const float* radj  = (const float*)d_in[1];
    const int*   inxs  = (const int*)  d_in[2];
    const float* Wq    = (const float*)d_in[3];
    const float* Wk    = (const float*)d_in[4];
    const float* Wv    = (const float*)d_in[5];
    const float* Wo    = (const float*)d_in[6];
    const float* ln1_g = (const float*)d_in[7];
    const float* ln1_b = (const float*)d_in[8];
    const float* W1    = (const float*)d_in[9];
    const float* b1    = (const float*)d_in[10];
    const float* W2    = (const float*)d_in[11];
    const float* b2    = (const float*)d_in[12];
    const float* ln2_g = (const float*)d_in[13];
    const float* ln2_b = (const float*)d_in[14];
    float* out = (float*)d_out;

    const size_t BTC = (size_t)B_ * T_ * C_;
    float* ws  = (float*)d_ws;
    float* h   = ws;              // B*T*C
    float* q   = ws + BTC;        // B*T*C   (attn output in-place; later y)
    float* kb  = ws + 2 * BTC;    // B*T*C   (later FFN hidden, spans kb+vb)
    float* vb  = ws + 3 * BTC;    // B*T*C
    float* hid = kb;              // B*T*H = 25.2M floats <= 33.5M (kb+vb)
    float* y   = q;               // after hops, q region holds y
    float* f   = h;               // after ln1, h region holds FFN output

    const int M = B_ * T_;
    const dim3 blk(256);
    const dim3 gC(C_ / 128, M / 128);   // N=1024 GEMMs
    const dim3 gH(H_ / 128, M / 128);   // N=1536 GEMM

    for (int hop = 0; hop < TNEI_; ++hop) {
        const float* hin = (hop == 0) ? x : h;
        sgemm_kernel<0, 0><<<gC, blk, 0, stream>>>(hin, Wq, nullptr, q,  M, C_, C_);
        sgemm_kernel<0, 0><<<gC, blk, 0, stream>>>(hin, Wk, nullptr, kb, M, C_, C_);
        sgemm_kernel<0, 0><<<gC, blk, 0, stream>>>(hin, Wv, nullptr, vb, M, C_, C_);
        attn_kernel<<<dim3(M), blk, 0, stream>>>(q, kb, vb, inxs, radj, q);
        sgemm_kernel<0, 0><<<gC, blk, 0, stream>>>(q, Wo, nullptr, h, M, C_, C_);
    }

    ln_residual_kernel<1><<<dim3(M), blk, 0, stream>>>(x, h, ln1_g, ln1_b, y);
    sgemm_kernel<1, 1><<<gH, blk, 0, stream>>>(y,   W1, b1, hid, M, H_, C_);
    sgemm_kernel<1, 0><<<gC, blk, 0, stream>>>(hid, W2, b2, f,   M, C_, H_);
    ln_residual_kernel<0><<<dim3(M), blk, 0, stream>>>(y, f, ln2_g, ln2_b, out);
}

// Round 2
// 1003.337 us; speedup vs baseline: 4.7097x; 4.7097x over previous
//
#include <hip/hip_runtime.h>
#include <hip/hip_bf16.h>
#include <cstddef>
#include <cstdint>

#define B_    16
#define T_    1024
#define C_    1024
#define K_    8
#define H_    1536
#define TNEI_ 2
static constexpr float EPS_ = 1e-5f;

typedef __attribute__((ext_vector_type(8))) short bf16x8;
typedef __attribute__((ext_vector_type(4))) float f32x4;

__device__ __forceinline__ float bf2f(unsigned short u) {
    return __uint_as_float(((unsigned)u) << 16);
}
__device__ __forceinline__ unsigned short f2bf(float f) {
    __hip_bfloat16 h = __float2bfloat16(f);
    union { __hip_bfloat16 h; unsigned short u; } cvt;
    cvt.h = h;
    return cvt.u;
}

__device__ __forceinline__ void gload_lds16(const void* g, void* l) {
    __builtin_amdgcn_global_load_lds(
        (const __attribute__((address_space(1))) void*)g,
        (__attribute__((address_space(3))) void*)l,
        16, 0, 0);
}

// ---------------------------------------------------------------------------
// f32 -> bf16 elementwise (4 per thread)
// ---------------------------------------------------------------------------
__global__ __launch_bounds__(256) void f2bf_kernel(
    const float* __restrict__ in, unsigned short* __restrict__ out)
{
    const size_t i = (size_t)blockIdx.x * 256 + threadIdx.x;
    const float4 v = *reinterpret_cast<const float4*>(&in[i * 4]);
    ushort4 o;
    o.x = f2bf(v.x); o.y = f2bf(v.y); o.z = f2bf(v.z); o.w = f2bf(v.w);
    *reinterpret_cast<ushort4*>(&out[i * 4]) = o;
}

// ---------------------------------------------------------------------------
// Transpose + convert: W (R x Cc, f32) -> WT (Cc x R, bf16)
// 32x32 tiles, 256 threads.
// ---------------------------------------------------------------------------
__global__ __launch_bounds__(256) void wtrans_kernel(
    const float* __restrict__ W, unsigned short* __restrict__ WT, int R, int Cc)
{
    __shared__ float t[32][33];
    const int c0 = blockIdx.x * 32, r0 = blockIdx.y * 32;
    const int tx = threadIdx.x & 31, ty = threadIdx.x >> 5;  // 32 x 8
    #pragma unroll
    for (int i = 0; i < 4; ++i)
        t[ty + 8 * i][tx] = W[(size_t)(r0 + ty + 8 * i) * Cc + c0 + tx];
    __syncthreads();
    #pragma unroll
    for (int i = 0; i < 4; ++i)
        WT[(size_t)(c0 + ty + 8 * i) * R + r0 + tx] = f2bf(t[tx][ty + 8 * i]);
}

// ---------------------------------------------------------------------------
// bf16 MFMA GEMM (m97 structure): C[M,N] = A[M,K] @ B[K,N] (+bias)(+relu)
//   A: M x K bf16 row-major     Bt: N x K bf16 row-major (pre-transposed B)
//   Cout: f32 (OUT_BF16=0) or bf16-as-ushort (OUT_BF16=1)
// 128x128 tile, BK=32, 256 threads = 4 waves (2x2), 64x64 per wave,
// acc 4x4 fragments of 16x16x32 MFMA, global_load_lds width 16.
// ---------------------------------------------------------------------------
template <int OUT_BF16, int BIAS, int RELU>
__global__ __launch_bounds__(256) void gemm_bt_kernel(
    const unsigned short* __restrict__ A, const unsigned short* __restrict__ Bt,
    const float* __restrict__ bias, void* __restrict__ Cout,
    int M, int N, int K)
{
    constexpr int BM = 128, BN = 128, BK = 32;
    __shared__ unsigned short As[BM * BK];   // 8 KB, rows of 32 bf16 (64 B)
    __shared__ unsigned short Bs[BN * BK];   // 8 KB

    const int tid  = threadIdx.x;
    const int lane = tid & 63;
    const int wid  = tid >> 6;              // 0..3
    const int wm   = wid >> 1, wn = wid & 1;
    const int row0 = blockIdx.y * BM;
    const int col0 = blockIdx.x * BN;

    const int sub = lane >> 2;              // 0..15 row-in-chunk
    const int kch = lane & 3;               // 16B chunk within 64B row

    f32x4 acc[4][4] = {};

    for (int kt = 0; kt < K; kt += BK) {
        #pragma unroll
        for (int i = 0; i < 2; ++i) {
            const int chunk = i * 4 + wid;          // 0..7 -> 16 rows each
            const int r = chunk * 16 + sub;
            gload_lds16(&A[(size_t)(row0 + r) * K + kt + kch * 8], &As[chunk * 512]);
        }
        #pragma unroll
        for (int i = 0; i < 2; ++i) {
            const int chunk = i * 4 + wid;
            const int r = chunk * 16 + sub;
            gload_lds16(&Bt[(size_t)(col0 + r) * K + kt + kch * 8], &Bs[chunk * 512]);
        }
        asm volatile("s_waitcnt vmcnt(0)" ::: "memory");
        __syncthreads();

        bf16x8 a[4], b[4];
        #pragma unroll
        for (int m = 0; m < 4; ++m) {
            const int r = wm * 64 + m * 16 + (lane & 15);
            a[m] = *reinterpret_cast<const bf16x8*>(&As[r * 32 + (lane >> 4) * 8]);
        }
        #pragma unroll
        for (int n = 0; n < 4; ++n) {
            const int c = wn * 64 + n * 16 + (lane & 15);
            b[n] = *reinterpret_cast<const bf16x8*>(&Bs[c * 32 + (lane >> 4) * 8]);
        }
        #pragma unroll
        for (int m = 0; m < 4; ++m)
            #pragma unroll
            for (int n = 0; n < 4; ++n)
                acc[m][n] = __builtin_amdgcn_mfma_f32_16x16x32_bf16(
                    a[m], b[n], acc[m][n], 0, 0, 0);
        __syncthreads();
    }

    // Epilogue: C/D layout col = lane&15, row = (lane>>4)*4 + reg  [m89/m91]
    #pragma unroll
    for (int m = 0; m < 4; ++m) {
        #pragma unroll
        for (int n = 0; n < 4; ++n) {
            const int cg = col0 + wn * 64 + n * 16 + (lane & 15);
            const float bv = BIAS ? bias[cg] : 0.0f;
            #pragma unroll
            for (int r = 0; r < 4; ++r) {
                const int rg = row0 + wm * 64 + m * 16 + (lane >> 4) * 4 + r;
                float v = acc[m][n][r] + bv;
                if (RELU) v = fmaxf(v, 0.0f);
                if (OUT_BF16)
                    ((unsigned short*)Cout)[(size_t)rg * N + cg] = f2bf(v);
                else
                    ((float*)Cout)[(size_t)rg * N + cg] = v;
            }
        }
    }
}

// ---------------------------------------------------------------------------
// Neighbor attention (bf16 q/k/v, f32 math, bf16 out). One block per (b,t).
// out may alias q (row-local).
// ---------------------------------------------------------------------------
__global__ __launch_bounds__(256) void attn_kernel(
    const unsigned short* __restrict__ q, const unsigned short* __restrict__ kbuf,
    const unsigned short* __restrict__ vbuf, const int* __restrict__ inxs,
    const float* __restrict__ radj, unsigned short* __restrict__ out)
{
    const int bt  = blockIdx.x;
    const int b   = bt >> 10;            // T = 1024
    const int tid = threadIdx.x;
    const float scale = 0.03125f;        // 1/sqrt(1024)

    __shared__ int   s_idx[K_];
    __shared__ float s_sc[K_];
    __shared__ float red[K_][4];

    if (tid < K_) s_idx[tid] = inxs[bt * K_ + tid];
    __syncthreads();

    const ushort4 qv = *reinterpret_cast<const ushort4*>(&q[(size_t)bt * C_ + tid * 4]);
    const float qf[4] = { bf2f(qv.x), bf2f(qv.y), bf2f(qv.z), bf2f(qv.w) };

    float part[K_];
    #pragma unroll
    for (int k = 0; k < K_; ++k) {
        const size_t nb = (size_t)b * T_ + s_idx[k];
        const ushort4 kv = *reinterpret_cast<const ushort4*>(&kbuf[nb * C_ + tid * 4]);
        part[k] = qf[0] * bf2f(kv.x) + qf[1] * bf2f(kv.y)
                + qf[2] * bf2f(kv.z) + qf[3] * bf2f(kv.w);
    }

    const int lane = tid & 63, wid = tid >> 6;
    #pragma unroll
    for (int k = 0; k < K_; ++k) {
        float v = part[k];
        #pragma unroll
        for (int off = 32; off; off >>= 1) v += __shfl_xor(v, off);
        if (lane == 0) red[k][wid] = v;
    }
    __syncthreads();
    if (tid < K_) {
        s_sc[tid] = (red[tid][0] + red[tid][1] + red[tid][2] + red[tid][3]) * scale
                    + radj[bt * K_ + tid];
    }
    __syncthreads();

    float m = s_sc[0];
    #pragma unroll
    for (int k = 1; k < K_; ++k) m = fmaxf(m, s_sc[k]);
    float w[K_], wsum = 0.f;
    #pragma unroll
    for (int k = 0; k < K_; ++k) { w[k] = expf(s_sc[k] - m); wsum += w[k]; }
    const float inv = 1.0f / wsum;

    float o[4] = {0.f, 0.f, 0.f, 0.f};
    #pragma unroll
    for (int k = 0; k < K_; ++k) {
        const size_t nb = (size_t)b * T_ + s_idx[k];
        const ushort4 vv = *reinterpret_cast<const ushort4*>(&vbuf[nb * C_ + tid * 4]);
        const float wk = w[k] * inv;
        o[0] = fmaf(wk, bf2f(vv.x), o[0]);
        o[1] = fmaf(wk, bf2f(vv.y), o[1]);
        o[2] = fmaf(wk, bf2f(vv.z), o[2]);
        o[3] = fmaf(wk, bf2f(vv.w), o[3]);
    }
    ushort4 ov;
    ov.x = f2bf(o[0]); ov.y = f2bf(o[1]); ov.z = f2bf(o[2]); ov.w = f2bf(o[3]);
    *reinterpret_cast<ushort4*>(&out[(size_t)bt * C_ + tid * 4]) = ov;
}

// ---------------------------------------------------------------------------
// out = LayerNorm(a + (RELU ? relu(b) : b)) * g + beta; optional bf16 copy.
// ---------------------------------------------------------------------------
template <int RELU, int WB>
__global__ __launch_bounds__(256) void ln_residual_kernel(
    const float* __restrict__ a, const float* __restrict__ bb,
    const float* __restrict__ g, const float* __restrict__ beta,
    float* __restrict__ out, unsigned short* __restrict__ outb)
{
    const int bt  = blockIdx.x;
    const int tid = threadIdx.x;

    const float4 av = *reinterpret_cast<const float4*>(&a[(size_t)bt * C_ + tid * 4]);
    const float4 bv = *reinterpret_cast<const float4*>(&bb[(size_t)bt * C_ + tid * 4]);
    float4 s;
    s.x = av.x + (RELU ? fmaxf(bv.x, 0.f) : bv.x);
    s.y = av.y + (RELU ? fmaxf(bv.y, 0.f) : bv.y);
    s.z = av.z + (RELU ? fmaxf(bv.z, 0.f) : bv.z);
    s.w = av.w + (RELU ? fmaxf(bv.w, 0.f) : bv.w);

    float sum = s.x + s.y + s.z + s.w;
    float sq  = s.x * s.x + s.y * s.y + s.z * s.z + s.w * s.w;

    const int lane = tid & 63, wid = tid >> 6;
    __shared__ float rs[4], rq[4];
    #pragma unroll
    for (int off = 32; off; off >>= 1) {
        sum += __shfl_xor(sum, off);
        sq  += __shfl_xor(sq,  off);
    }
    if (lane == 0) { rs[wid] = sum; rq[wid] = sq; }
    __syncthreads();
    sum = rs[0] + rs[1] + rs[2] + rs[3];
    sq  = rq[0] + rq[1] + rq[2] + rq[3];

    const float mu  = sum * (1.0f / C_);
    const float var = sq * (1.0f / C_) - mu * mu;
    const float r   = rsqrtf(var + EPS_);

    const float4 gv = *reinterpret_cast<const float4*>(&g[tid * 4]);
    const float4 be = *reinterpret_cast<const float4*>(&beta[tid * 4]);
    float4 o;
    o.x = (s.x - mu) * r * gv.x + be.x;
    o.y = (s.y - mu) * r * gv.y + be.y;
    o.z = (s.z - mu) * r * gv.z + be.z;
    o.w = (s.w - mu) * r * gv.w + be.w;
    *reinterpret_cast<float4*>(&out[(size_t)bt * C_ + tid * 4]) = o;
    if (WB) {
        ushort4 ob;
        ob.x = f2bf(o.x); ob.y = f2bf(o.y); ob.z = f2bf(o.z); ob.w = f2bf(o.w);
        *reinterpret_cast<ushort4*>(&outb[(size_t)bt * C_ + tid * 4]) = ob;
    }
}

// ---------------------------------------------------------------------------
extern "C" void kernel_launch(void* const* d_in, const int* in_sizes, int n_in,
                              void* d_out, int out_size, void* d_ws, size_t ws_size,
                              hipStream_t stream)
{
    const float* x     = (const float*)d_in[0];
    const float* radj  = (const float*)d_in[1];
    const int*   inxs  = (const int*)  d_in[2];
    const float* Wq    = (const float*)d_in[3];
    const float* Wk    = (const float*)d_in[4];
    const float* Wv    = (const float*)d_in[5];
    const float* Wo    = (const float*)d_in[6];
    const float* ln1_g = (const float*)d_in[7];
    const float* ln1_b = (const float*)d_in[8];
    const float* W1    = (const float*)d_in[9];
    const float* b1    = (const float*)d_in[10];
    const float* W2    = (const float*)d_in[11];
    const float* b2    = (const float*)d_in[12];
    const float* ln2_g = (const float*)d_in[13];
    const float* ln2_b = (const float*)d_in[14];
    float* out = (float*)d_out;

    char* wsb = (char*)d_ws;
    const size_t MB = 1 << 20;
    // Weight area (bf16, pre-transposed to N x K): 0..16 MB
    unsigned short* WqT = (unsigned short*)(wsb + 0 * MB);
    unsigned short* WkT = (unsigned short*)(wsb + 2 * MB);
    unsigned short* WvT = (unsigned short*)(wsb + 4 * MB);
    unsigned short* WoT = (unsigned short*)(wsb + 6 * MB);
    unsigned short* W1T = (unsigned short*)(wsb + 8 * MB);   // H x C, 3 MB
    unsigned short* W2T = (unsigned short*)(wsb + 11 * MB);  // C x H, 3 MB
    // Activations
    unsigned short* xb  = (unsigned short*)(wsb + 16 * MB);  // 32 MB; later h_b
    unsigned short* hb  = xb;                                // hop state (bf16)
    unsigned short* qb  = (unsigned short*)(wsb + 48 * MB);  // 32 MB; attn out in-place
    unsigned short* kb  = (unsigned short*)(wsb + 80 * MB);  // 32 MB
    unsigned short* vb  = (unsigned short*)(wsb + 112 * MB); // 32 MB
    float*          h2  = (float*)(wsb + 144 * MB);          // 64 MB (hop2 Wo out, f32)
    float*          y   = (float*)(wsb + 48 * MB);           // 64 MB (over qb+kb)
    unsigned short* yb  = (unsigned short*)(wsb + 112 * MB); // 32 MB (over vb)
    unsigned short* hid = (unsigned short*)(wsb + 144 * MB); // 48 MB (over h2)
    float*          f   = (float*)(wsb + 192 * MB);          // 64 MB

    const int M = B_ * T_;
    const dim3 blk(256);
    const dim3 gC(C_ / 128, M / 128);
    const dim3 gH(H_ / 128, M / 128);

    // --- weight + input conversion (each launch; ws is re-poisoned) ---
    wtrans_kernel<<<dim3(32, 32), blk, 0, stream>>>(Wq, WqT, C_, C_);
    wtrans_kernel<<<dim3(32, 32), blk, 0, stream>>>(Wk, WkT, C_, C_);
    wtrans_kernel<<<dim3(32, 32), blk, 0, stream>>>(Wv, WvT, C_, C_);
    wtrans_kernel<<<dim3(32, 32), blk, 0, stream>>>(Wo, WoT, C_, C_);
    wtrans_kernel<<<dim3(48, 32), blk, 0, stream>>>(W1, W1T, C_, H_);   // -> H x C
    wtrans_kernel<<<dim3(32, 48), blk, 0, stream>>>(W2, W2T, H_, C_);   // -> C x H
    f2bf_kernel<<<dim3((size_t)M * C_ / 1024), blk, 0, stream>>>(x, xb);

    // --- hops ---
    for (int hop = 0; hop < TNEI_; ++hop) {
        const unsigned short* hin = (hop == 0) ? xb : hb;
        gemm_bt_kernel<1, 0, 0><<<gC, blk, 0, stream>>>(hin, WqT, nullptr, qb, M, C_, C_);
        gemm_bt_kernel<1, 0, 0><<<gC, blk, 0, stream>>>(hin, WkT, nullptr, kb, M, C_, C_);
        gemm_bt_kernel<1, 0, 0><<<gC, blk, 0, stream>>>(hin, WvT, nullptr, vb, M, C_, C_);
        attn_kernel<<<dim3(M), blk, 0, stream>>>(qb, kb, vb, inxs, radj, qb);
        if (hop == 0)
            gemm_bt_kernel<1, 0, 0><<<gC, blk, 0, stream>>>(qb, WoT, nullptr, hb, M, C_, C_);
        else
            gemm_bt_kernel<0, 0, 0><<<gC, blk, 0, stream>>>(qb, WoT, nullptr, h2, M, C_, C_);
    }

    // --- residual + LN1 (writes f32 y and bf16 yb) ---
    ln_residual_kernel<1, 1><<<dim3(M), blk, 0, stream>>>(x, h2, ln1_g, ln1_b, y, yb);
    // --- FFN ---
    gemm_bt_kernel<1, 1, 1><<<gH, blk, 0, stream>>>(yb,  W1T, b1, hid, M, H_, C_);
    gemm_bt_kernel<0, 1, 0><<<gC, blk, 0, stream>>>(hid, W2T, b2, f,   M, C_, H_);
    // --- residual + LN2 ---
    ln_residual_kernel<0, 0><<<dim3(M), blk, 0, stream>>>(y, f, ln2_g, ln2_b, out, nullptr);
}

// Round 3
// 887.702 us; speedup vs baseline: 5.3232x; 1.1303x over previous
//
#include <hip/hip_runtime.h>
#include <hip/hip_bf16.h>
#include <cstddef>
#include <cstdint>

#define B_    16
#define T_    1024
#define C_    1024
#define K_    8
#define H_    1536
#define TNEI_ 2
static constexpr float EPS_ = 1e-5f;

typedef __attribute__((ext_vector_type(8))) short bf16x8;
typedef __attribute__((ext_vector_type(4))) float f32x4;

__device__ __forceinline__ float bf2f(unsigned short u) {
    return __uint_as_float(((unsigned)u) << 16);
}
__device__ __forceinline__ unsigned short f2bf(float f) {
    __hip_bfloat16 h = __float2bfloat16(f);
    union { __hip_bfloat16 h; unsigned short u; } cvt;
    cvt.h = h;
    return cvt.u;
}

__device__ __forceinline__ void gload_lds16(const void* g, void* l) {
    __builtin_amdgcn_global_load_lds(
        (const __attribute__((address_space(1))) void*)g,
        (__attribute__((address_space(3))) void*)l,
        16, 0, 0);
}

// ---------------------------------------------------------------------------
// f32 -> bf16 elementwise (4 per thread)
// ---------------------------------------------------------------------------
__global__ __launch_bounds__(256) void f2bf_kernel(
    const float* __restrict__ in, unsigned short* __restrict__ out)
{
    const size_t i = (size_t)blockIdx.x * 256 + threadIdx.x;
    const float4 v = *reinterpret_cast<const float4*>(&in[i * 4]);
    ushort4 o;
    o.x = f2bf(v.x); o.y = f2bf(v.y); o.z = f2bf(v.z); o.w = f2bf(v.w);
    *reinterpret_cast<ushort4*>(&out[i * 4]) = o;
}

// ---------------------------------------------------------------------------
// Transpose + convert: W (R x Cc, f32) -> WT (Cc x R, bf16)
// ---------------------------------------------------------------------------
__global__ __launch_bounds__(256) void wtrans_kernel(
    const float* __restrict__ W, unsigned short* __restrict__ WT, int R, int Cc)
{
    __shared__ float t[32][33];
    const int c0 = blockIdx.x * 32, r0 = blockIdx.y * 32;
    const int tx = threadIdx.x & 31, ty = threadIdx.x >> 5;  // 32 x 8
    #pragma unroll
    for (int i = 0; i < 4; ++i)
        t[ty + 8 * i][tx] = W[(size_t)(r0 + ty + 8 * i) * Cc + c0 + tx];
    __syncthreads();
    #pragma unroll
    for (int i = 0; i < 4; ++i)
        WT[(size_t)(c0 + ty + 8 * i) * R + r0 + tx] = f2bf(t[tx][ty + 8 * i]);
}

// ---------------------------------------------------------------------------
// bf16 MFMA GEMM, 2-phase double-buffered, XCD-chunk-swizzled.
//   C[M,N] = A[M,K] @ Bt[N,K]^T (+bias)(+relu)
// 128x128 tile, BK=32, 256 threads = 4 waves (2x2), 64x64/wave,
// 4x4 frags of mfma_f32_16x16x32_bf16, global_load_lds width 16.
// Requires (gridDim.x*gridDim.y) % 8 == 0.
// ---------------------------------------------------------------------------
template <int OUT_BF16, int BIAS, int RELU>
__global__ __launch_bounds__(256) void gemm_bt_kernel(
    const unsigned short* __restrict__ A, const unsigned short* __restrict__ Bt,
    const float* __restrict__ bias, void* __restrict__ Cout,
    int M, int N, int K)
{
    constexpr int BM = 128, BN = 128, BK = 32;
    __shared__ unsigned short smem[2 * (BM * BK + BN * BK)];  // 32 KB

    const int tid  = threadIdx.x;
    const int lane = tid & 63;
    const int wid  = tid >> 6;
    const int wm   = wid >> 1, wn = wid & 1;

    // T1: chunked XCD swizzle (bijective; nwg % 8 == 0 for all our grids)
    const int nwg  = gridDim.x * gridDim.y;
    int bidl = blockIdx.y * gridDim.x + blockIdx.x;
    bidl = (bidl & 7) * (nwg >> 3) + (bidl >> 3);
    const int bx = bidl % gridDim.x;
    const int by = bidl / gridDim.x;
    const int row0 = by * BM;
    const int col0 = bx * BN;

    const int sub = lane >> 2;   // 0..15 row within 16-row chunk
    const int kch = lane & 3;    // 16B chunk within 64B LDS row

    f32x4 acc[4][4] = {};

    auto stage = [&](int buf, int kt) {
        unsigned short* As = smem + buf * 8192;
        unsigned short* Bs = As + 4096;
        #pragma unroll
        for (int i = 0; i < 2; ++i) {
            const int chunk = i * 4 + wid;       // 0..7, 16 rows each
            const int r = chunk * 16 + sub;
            gload_lds16(&A[(size_t)(row0 + r) * K + kt + kch * 8], &As[chunk * 512]);
        }
        #pragma unroll
        for (int i = 0; i < 2; ++i) {
            const int chunk = i * 4 + wid;
            const int r = chunk * 16 + sub;
            gload_lds16(&Bt[(size_t)(col0 + r) * K + kt + kch * 8], &Bs[chunk * 512]);
        }
    };

    auto compute = [&](int buf) {
        const unsigned short* As = smem + buf * 8192;
        const unsigned short* Bs = As + 4096;
        bf16x8 a[4], b[4];
        #pragma unroll
        for (int m = 0; m < 4; ++m) {
            const int r = wm * 64 + m * 16 + (lane & 15);
            a[m] = *reinterpret_cast<const bf16x8*>(&As[r * 32 + (lane >> 4) * 8]);
        }
        #pragma unroll
        for (int n = 0; n < 4; ++n) {
            const int c = wn * 64 + n * 16 + (lane & 15);
            b[n] = *reinterpret_cast<const bf16x8*>(&Bs[c * 32 + (lane >> 4) * 8]);
        }
        #pragma unroll
        for (int m = 0; m < 4; ++m)
            #pragma unroll
            for (int n = 0; n < 4; ++n)
                acc[m][n] = __builtin_amdgcn_mfma_f32_16x16x32_bf16(
                    a[m], b[n], acc[m][n], 0, 0, 0);
    };

    // prologue
    stage(0, 0);
    asm volatile("s_waitcnt vmcnt(0)" ::: "memory");
    __syncthreads();
    int cur = 0;
    for (int kt = BK; kt < K; kt += BK) {
        stage(cur ^ 1, kt);          // prefetch next tile (overlaps compute)
        compute(cur);
        asm volatile("s_waitcnt vmcnt(0)" ::: "memory");
        __syncthreads();
        cur ^= 1;
    }
    compute(cur);

    // ------------------------------------------------------------------
    // Epilogue. C/D layout: col = lane&15, row = (lane>>4)*4 + reg.
    // ------------------------------------------------------------------
    if (OUT_BF16) {
        __syncthreads();                       // LDS free for reuse
        char* tile = (char*)smem;              // [128][128] ushort, XOR-swizzled
        #pragma unroll
        for (int m = 0; m < 4; ++m) {
            #pragma unroll
            for (int n = 0; n < 4; ++n) {
                const int cc = wn * 64 + n * 16 + (lane & 15);
                const float bv = BIAS ? bias[col0 + cc] : 0.0f;
                #pragma unroll
                for (int r = 0; r < 4; ++r) {
                    const int rr = wm * 64 + m * 16 + (lane >> 4) * 4 + r;
                    float v = acc[m][n][r] + bv;
                    if (RELU) v = fmaxf(v, 0.0f);
                    const int byte = (rr * 256 + cc * 2) ^ (((rr >> 2) & 3) << 5);
                    *reinterpret_cast<unsigned short*>(tile + byte) = f2bf(v);
                }
            }
        }
        __syncthreads();
        const int cchunk = tid & 15;           // 16B (8-col) chunk
        const int rloc   = tid >> 4;           // 0..15
        #pragma unroll
        for (int p = 0; p < 8; ++p) {
            const int rr = p * 16 + rloc;
            const int byte = (rr * 256 + cchunk * 16) ^ (((rr >> 2) & 3) << 5);
            const uint4 v = *reinterpret_cast<const uint4*>(tile + byte);
            *reinterpret_cast<uint4*>(
                &((unsigned short*)Cout)[(size_t)(row0 + rr) * N + col0 + cchunk * 8]) = v;
        }
    } else {
        #pragma unroll
        for (int m = 0; m < 4; ++m) {
            #pragma unroll
            for (int n = 0; n < 4; ++n) {
                const int cg = col0 + wn * 64 + n * 16 + (lane & 15);
                const float bv = BIAS ? bias[cg] : 0.0f;
                #pragma unroll
                for (int r = 0; r < 4; ++r) {
                    const int rg = row0 + wm * 64 + m * 16 + (lane >> 4) * 4 + r;
                    float v = acc[m][n][r] + bv;
                    if (RELU) v = fmaxf(v, 0.0f);
                    ((float*)Cout)[(size_t)rg * N + cg] = v;
                }
            }
        }
    }
}

// ---------------------------------------------------------------------------
// Neighbor attention (bf16 q/k/v, f32 math, bf16 out). One block per (b,t).
// out may alias q (row-local).
// ---------------------------------------------------------------------------
__global__ __launch_bounds__(256) void attn_kernel(
    const unsigned short* __restrict__ q, const unsigned short* __restrict__ kbuf,
    const unsigned short* __restrict__ vbuf, const int* __restrict__ inxs,
    const float* __restrict__ radj, unsigned short* __restrict__ out)
{
    const int bt  = blockIdx.x;
    const int b   = bt >> 10;            // T = 1024
    const int tid = threadIdx.x;
    const float scale = 0.03125f;        // 1/sqrt(1024)

    __shared__ int   s_idx[K_];
    __shared__ float s_sc[K_];
    __shared__ float red[K_][4];

    if (tid < K_) s_idx[tid] = inxs[bt * K_ + tid];
    __syncthreads();

    const ushort4 qv = *reinterpret_cast<const ushort4*>(&q[(size_t)bt * C_ + tid * 4]);
    const float qf[4] = { bf2f(qv.x), bf2f(qv.y), bf2f(qv.z), bf2f(qv.w) };

    float part[K_];
    #pragma unroll
    for (int k = 0; k < K_; ++k) {
        const size_t nb = (size_t)b * T_ + s_idx[k];
        const ushort4 kv = *reinterpret_cast<const ushort4*>(&kbuf[nb * C_ + tid * 4]);
        part[k] = qf[0] * bf2f(kv.x) + qf[1] * bf2f(kv.y)
                + qf[2] * bf2f(kv.z) + qf[3] * bf2f(kv.w);
    }

    const int lane = tid & 63, wid = tid >> 6;
    #pragma unroll
    for (int k = 0; k < K_; ++k) {
        float v = part[k];
        #pragma unroll
        for (int off = 32; off; off >>= 1) v += __shfl_xor(v, off);
        if (lane == 0) red[k][wid] = v;
    }
    __syncthreads();
    if (tid < K_) {
        s_sc[tid] = (red[tid][0] + red[tid][1] + red[tid][2] + red[tid][3]) * scale
                    + radj[bt * K_ + tid];
    }
    __syncthreads();

    float m = s_sc[0];
    #pragma unroll
    for (int k = 1; k < K_; ++k) m = fmaxf(m, s_sc[k]);
    float w[K_], wsum = 0.f;
    #pragma unroll
    for (int k = 0; k < K_; ++k) { w[k] = expf(s_sc[k] - m); wsum += w[k]; }
    const float inv = 1.0f / wsum;

    float o[4] = {0.f, 0.f, 0.f, 0.f};
    #pragma unroll
    for (int k = 0; k < K_; ++k) {
        const size_t nb = (size_t)b * T_ + s_idx[k];
        const ushort4 vv = *reinterpret_cast<const ushort4*>(&vbuf[nb * C_ + tid * 4]);
        const float wk = w[k] * inv;
        o[0] = fmaf(wk, bf2f(vv.x), o[0]);
        o[1] = fmaf(wk, bf2f(vv.y), o[1]);
        o[2] = fmaf(wk, bf2f(vv.z), o[2]);
        o[3] = fmaf(wk, bf2f(vv.w), o[3]);
    }
    ushort4 ov;
    ov.x = f2bf(o[0]); ov.y = f2bf(o[1]); ov.z = f2bf(o[2]); ov.w = f2bf(o[3]);
    *reinterpret_cast<ushort4*>(&out[(size_t)bt * C_ + tid * 4]) = ov;
}

// ---------------------------------------------------------------------------
// out = LayerNorm(a + (RELU ? relu(b) : b)) * g + beta; optional bf16 copy.
// ---------------------------------------------------------------------------
template <int RELU, int WB>
__global__ __launch_bounds__(256) void ln_residual_kernel(
    const float* __restrict__ a, const float* __restrict__ bb,
    const float* __restrict__ g, const float* __restrict__ beta,
    float* __restrict__ out, unsigned short* __restrict__ outb)
{
    const int bt  = blockIdx.x;
    const int tid = threadIdx.x;

    const float4 av = *reinterpret_cast<const float4*>(&a[(size_t)bt * C_ + tid * 4]);
    const float4 bv = *reinterpret_cast<const float4*>(&bb[(size_t)bt * C_ + tid * 4]);
    float4 s;
    s.x = av.x + (RELU ? fmaxf(bv.x, 0.f) : bv.x);
    s.y = av.y + (RELU ? fmaxf(bv.y, 0.f) : bv.y);
    s.z = av.z + (RELU ? fmaxf(bv.z, 0.f) : bv.z);
    s.w = av.w + (RELU ? fmaxf(bv.w, 0.f) : bv.w);

    float sum = s.x + s.y + s.z + s.w;
    float sq  = s.x * s.x + s.y * s.y + s.z * s.z + s.w * s.w;

    const int lane = tid & 63, wid = tid >> 6;
    __shared__ float rs[4], rq[4];
    #pragma unroll
    for (int off = 32; off; off >>= 1) {
        sum += __shfl_xor(sum, off);
        sq  += __shfl_xor(sq,  off);
    }
    if (lane == 0) { rs[wid] = sum; rq[wid] = sq; }
    __syncthreads();
    sum = rs[0] + rs[1] + rs[2] + rs[3];
    sq  = rq[0] + rq[1] + rq[2] + rq[3];

    const float mu  = sum * (1.0f / C_);
    const float var = sq * (1.0f / C_) - mu * mu;
    const float r   = rsqrtf(var + EPS_);

    const float4 gv = *reinterpret_cast<const float4*>(&g[tid * 4]);
    const float4 be = *reinterpret_cast<const float4*>(&beta[tid * 4]);
    float4 o;
    o.x = (s.x - mu) * r * gv.x + be.x;
    o.y = (s.y - mu) * r * gv.y + be.y;
    o.z = (s.z - mu) * r * gv.z + be.z;
    o.w = (s.w - mu) * r * gv.w + be.w;
    *reinterpret_cast<float4*>(&out[(size_t)bt * C_ + tid * 4]) = o;
    if (WB) {
        ushort4 ob;
        ob.x = f2bf(o.x); ob.y = f2bf(o.y); ob.z = f2bf(o.z); ob.w = f2bf(o.w);
        *reinterpret_cast<ushort4*>(&outb[(size_t)bt * C_ + tid * 4]) = ob;
    }
}

// ---------------------------------------------------------------------------
extern "C" void kernel_launch(void* const* d_in, const int* in_sizes, int n_in,
                              void* d_out, int out_size, void* d_ws, size_t ws_size,
                              hipStream_t stream)
{
    const float* x     = (const float*)d_in[0];
    const float* radj  = (const float*)d_in[1];
    const int*   inxs  = (const int*)  d_in[2];
    const float* Wq    = (const float*)d_in[3];
    const float* Wk    = (const float*)d_in[4];
    const float* Wv    = (const float*)d_in[5];
    const float* Wo    = (const float*)d_in[6];
    const float* ln1_g = (const float*)d_in[7];
    const float* ln1_b = (const float*)d_in[8];
    const float* W1    = (const float*)d_in[9];
    const float* b1    = (const float*)d_in[10];
    const float* W2    = (const float*)d_in[11];
    const float* b2    = (const float*)d_in[12];
    const float* ln2_g = (const float*)d_in[13];
    const float* ln2_b = (const float*)d_in[14];
    float* out = (float*)d_out;

    char* wsb = (char*)d_ws;
    const size_t MB = 1 << 20;
    unsigned short* WqT = (unsigned short*)(wsb + 0 * MB);
    unsigned short* WkT = (unsigned short*)(wsb + 2 * MB);
    unsigned short* WvT = (unsigned short*)(wsb + 4 * MB);
    unsigned short* WoT = (unsigned short*)(wsb + 6 * MB);
    unsigned short* W1T = (unsigned short*)(wsb + 8 * MB);   // H x C, 3 MB
    unsigned short* W2T = (unsigned short*)(wsb + 11 * MB);  // C x H, 3 MB
    unsigned short* xb  = (unsigned short*)(wsb + 16 * MB);  // 32 MB; hop state
    unsigned short* hb  = xb;
    unsigned short* qb  = (unsigned short*)(wsb + 48 * MB);  // 32 MB
    unsigned short* kb  = (unsigned short*)(wsb + 80 * MB);  // 32 MB
    unsigned short* vb  = (unsigned short*)(wsb + 112 * MB); // 32 MB
    float*          h2  = (float*)(wsb + 144 * MB);          // 64 MB (hop2 out, f32)
    float*          y   = (float*)(wsb + 48 * MB);           // 64 MB (over qb+kb)
    unsigned short* yb  = (unsigned short*)(wsb + 112 * MB); // 32 MB (over vb)
    unsigned short* hid = (unsigned short*)(wsb + 144 * MB); // 48 MB (over h2)
    float*          f   = (float*)(wsb + 192 * MB);          // 64 MB

    const int M = B_ * T_;
    const dim3 blk(256);
    const dim3 gC(C_ / 128, M / 128);
    const dim3 gH(H_ / 128, M / 128);

    wtrans_kernel<<<dim3(32, 32), blk, 0, stream>>>(Wq, WqT, C_, C_);
    wtrans_kernel<<<dim3(32, 32), blk, 0, stream>>>(Wk, WkT, C_, C_);
    wtrans_kernel<<<dim3(32, 32), blk, 0, stream>>>(Wv, WvT, C_, C_);
    wtrans_kernel<<<dim3(32, 32), blk, 0, stream>>>(Wo, WoT, C_, C_);
    wtrans_kernel<<<dim3(48, 32), blk, 0, stream>>>(W1, W1T, C_, H_);   // -> H x C
    wtrans_kernel<<<dim3(32, 48), blk, 0, stream>>>(W2, W2T, H_, C_);   // -> C x H
    f2bf_kernel<<<dim3((size_t)M * C_ / 1024), blk, 0, stream>>>(x, xb);

    for (int hop = 0; hop < TNEI_; ++hop) {
        const unsigned short* hin = (hop == 0) ? xb : hb;
        gemm_bt_kernel<1, 0, 0><<<gC, blk, 0, stream>>>(hin, WqT, nullptr, qb, M, C_, C_);
        gemm_bt_kernel<1, 0, 0><<<gC, blk, 0, stream>>>(hin, WkT, nullptr, kb, M, C_, C_);
        gemm_bt_kernel<1, 0, 0><<<gC, blk, 0, stream>>>(hin, WvT, nullptr, vb, M, C_, C_);
        attn_kernel<<<dim3(M), blk, 0, stream>>>(qb, kb, vb, inxs, radj, qb);
        if (hop == 0)
            gemm_bt_kernel<1, 0, 0><<<gC, blk, 0, stream>>>(qb, WoT, nullptr, hb, M, C_, C_);
        else
            gemm_bt_kernel<0, 0, 0><<<gC, blk, 0, stream>>>(qb, WoT, nullptr, h2, M, C_, C_);
    }

    ln_residual_kernel<1, 1><<<dim3(M), blk, 0, stream>>>(x, h2, ln1_g, ln1_b, y, yb);
    gemm_bt_kernel<1, 1, 1><<<gH, blk, 0, stream>>>(yb,  W1T, b1, hid, M, H_, C_);
    gemm_bt_kernel<0, 1, 0><<<gC, blk, 0, stream>>>(hid, W2T, b2, f,   M, C_, H_);
    ln_residual_kernel<0, 0><<<dim3(M), blk, 0, stream>>>(y, f, ln2_g, ln2_b, out, nullptr);
}

// Round 5
// 801.795 us; speedup vs baseline: 5.8936x; 1.1071x over previous
//
#include <hip/hip_runtime.h>
#include <hip/hip_bf16.h>
#include <cstddef>
#include <cstdint>

#define B_    16
#define T_    1024
#define C_    1024
#define K_    8
#define H_    1536
#define TNEI_ 2
static constexpr float EPS_ = 1e-5f;

typedef __attribute__((ext_vector_type(8))) short bf16x8;
typedef __attribute__((ext_vector_type(4))) float f32x4;

__device__ __forceinline__ float bf2f(unsigned short u) {
    return __uint_as_float(((unsigned)u) << 16);
}
__device__ __forceinline__ unsigned short f2bf(float f) {
    __hip_bfloat16 h = __float2bfloat16(f);
    union { __hip_bfloat16 h; unsigned short u; } cvt;
    cvt.h = h;
    return cvt.u;
}

__device__ __forceinline__ void gload_lds16(const void* g, void* l) {
    __builtin_amdgcn_global_load_lds(
        (const __attribute__((address_space(1))) void*)g,
        (__attribute__((address_space(3))) void*)l,
        16, 0, 0);
}

#define VMCNT0 asm volatile("s_waitcnt vmcnt(0)" ::: "memory")
#define VMCNT4 asm volatile("s_waitcnt vmcnt(4)" ::: "memory")
// raw barrier + compiler fences: no memory op may be hoisted across
#define BARRIER do {                                   \
    __builtin_amdgcn_sched_barrier(0);                 \
    __builtin_amdgcn_s_barrier();                      \
    asm volatile("" ::: "memory");                     \
    __builtin_amdgcn_sched_barrier(0);                 \
} while (0)

// ---------------------------------------------------------------------------
// f32 -> bf16 elementwise (4 per thread)
// ---------------------------------------------------------------------------
__global__ __launch_bounds__(256) void f2bf_kernel(
    const float* __restrict__ in, unsigned short* __restrict__ out)
{
    const size_t i = (size_t)blockIdx.x * 256 + threadIdx.x;
    const float4 v = *reinterpret_cast<const float4*>(&in[i * 4]);
    ushort4 o;
    o.x = f2bf(v.x); o.y = f2bf(v.y); o.z = f2bf(v.z); o.w = f2bf(v.w);
    *reinterpret_cast<ushort4*>(&out[i * 4]) = o;
}

// ---------------------------------------------------------------------------
// Transpose + convert: W (R x Cc, f32) -> WT (Cc x R, bf16)
// ---------------------------------------------------------------------------
__global__ __launch_bounds__(256) void wtrans_kernel(
    const float* __restrict__ W, unsigned short* __restrict__ WT, int R, int Cc)
{
    __shared__ float t[32][33];
    const int c0 = blockIdx.x * 32, r0 = blockIdx.y * 32;
    const int tx = threadIdx.x & 31, ty = threadIdx.x >> 5;  // 32 x 8
    #pragma unroll
    for (int i = 0; i < 4; ++i)
        t[ty + 8 * i][tx] = W[(size_t)(r0 + ty + 8 * i) * Cc + c0 + tx];
    __syncthreads();
    #pragma unroll
    for (int i = 0; i < 4; ++i)
        WT[(size_t)(c0 + ty + 8 * i) * R + r0 + tx] = f2bf(t[tx][ty + 8 * i]);
}

// ---------------------------------------------------------------------------
// bf16 MFMA GEMM: triple-buffered, distance-2 prefetch, counted vmcnt.
//   C[M,N] = A[M,K] @ Bt[N,K]^T (+bias)(+relu)
// 128x128 tile, BK=32, 256 threads = 4 waves (2x2), 64x64/wave.
//
// Phase t:  stage(t+2) -> buf[(t+2)%3]          (4 gload_lds / thread)
//           mfma(tile t) from regs               (auto-lgkm drains prev reads)
//           vmcnt(4)  -> own tile-(t+1) loads done (t+2 stays in flight, T4)
//           s_barrier -> ALL waves' tile-(t+1) loads confirmed
//           loadfrag(t+1) -> regs                (reads strictly after barrier)
// WAR safety: stage(t+2) reuses the buffer of tile t-1, whose ds_reads were
// consumed by mfma(t-1) (compiler auto-lgkmcnt) before barrier(t-1) in every
// wave. RAW safety: per-wave vmcnt before the barrier + read after it.
// T2 swizzle: LDS[R][S] holds global k-chunk S ^ (((R&15)>>1)&3); applied on
// the gload *source* (dest stays linear, rule #21) and on the ds_read slot.
// Requires (gridDim.x*gridDim.y)%8==0, K%64==0, M%128==0, N%128==0.
// ---------------------------------------------------------------------------
template <int OUT_BF16, int BIAS, int RELU>
__global__ __launch_bounds__(256, 2) void gemm_bt_kernel(
    const unsigned short* __restrict__ A, const unsigned short* __restrict__ Bt,
    const float* __restrict__ bias, void* __restrict__ Cout,
    int M, int N, int K)
{
    constexpr int BK = 32;
    __shared__ unsigned short smem[3 * 8192];   // 3 bufs x (A 8KB + B 8KB) = 48 KB

    const int tid  = threadIdx.x;
    const int lane = tid & 63;
    const int wid  = tid >> 6;
    const int wm   = wid >> 1, wn = wid & 1;

    // T1: chunked XCD swizzle (bijective; nwg % 8 == 0 for all our grids)
    const int nwg  = gridDim.x * gridDim.y;
    int bidl = blockIdx.y * gridDim.x + blockIdx.x;
    bidl = (bidl & 7) * (nwg >> 3) + (bidl >> 3);
    const int bx = bidl % gridDim.x;
    const int by = bidl / gridDim.x;
    const int row0 = by * 128;
    const int col0 = bx * 128;

    const int NT = K >> 5;                    // 32 (K=1024) or 48 (K=1536), even

    // staging: 4 gloads/thread/tile; source k-chunk pre-swizzled (T2 inverse)
    const int sub = lane >> 2;                // row within 16-row chunk
    const int kk  = (((lane & 3) ^ ((lane >> 3) & 3))) * 8;

    f32x4 acc[4][4] = {};

    auto stage = [&](int kt, int bufi) {
        unsigned short* As = smem + bufi * 8192;
        unsigned short* Bs = As + 4096;
        #pragma unroll
        for (int i = 0; i < 2; ++i) {
            const int chunk = i * 4 + wid;
            const int r = chunk * 16 + sub;
            gload_lds16(&A[(size_t)(row0 + r) * K + kt + kk], &As[chunk * 512]);
        }
        #pragma unroll
        for (int i = 0; i < 2; ++i) {
            const int chunk = i * 4 + wid;
            const int r = chunk * 16 + sub;
            gload_lds16(&Bt[(size_t)(col0 + r) * K + kt + kk], &Bs[chunk * 512]);
        }
    };

    const int slot = ((lane >> 4) ^ ((lane >> 1) & 3)) * 8;  // T2 read swizzle
    auto loadfrag = [&](int bufi, bf16x8* a, bf16x8* b) {
        const unsigned short* As = smem + bufi * 8192;
        const unsigned short* Bs = As + 4096;
        #pragma unroll
        for (int m = 0; m < 4; ++m) {
            const int r = wm * 64 + m * 16 + (lane & 15);
            a[m] = *reinterpret_cast<const bf16x8*>(&As[r * 32 + slot]);
        }
        #pragma unroll
        for (int n = 0; n < 4; ++n) {
            const int c = wn * 64 + n * 16 + (lane & 15);
            b[n] = *reinterpret_cast<const bf16x8*>(&Bs[c * 32 + slot]);
        }
    };

    auto mfma16 = [&](const bf16x8* a, const bf16x8* b) {
        __builtin_amdgcn_s_setprio(1);
        #pragma unroll
        for (int m = 0; m < 4; ++m)
            #pragma unroll
            for (int n = 0; n < 4; ++n)
                acc[m][n] = __builtin_amdgcn_mfma_f32_16x16x32_bf16(
                    a[m], b[n], acc[m][n], 0, 0, 0);
        __builtin_amdgcn_s_setprio(0);
    };

    bf16x8 fa[4], fb[4];

    // prologue: stage tiles 0,1; confirm tile 0 (all waves) before first read
    stage(0, 0);
    stage(BK, 1);
    VMCNT4;                 // own tile-0 loads done; tile 1 in flight
    BARRIER;                // every wave's tile-0 loads confirmed
    loadfrag(0, fa, fb);

    int bs = 2, br = 1;     // stage buf = (t+2)%3, read buf = (t+1)%3
    for (int t = 0; t < NT; ++t) {
        if (t + 2 < NT) stage((t + 2) * BK, bs);
        if (++bs == 3) bs = 0;
        mfma16(fa, fb);     // consumes loadfrag(t); auto-lgkm drains ds_reads
        if (t + 1 < NT) {
            if (t + 2 < NT) { VMCNT4; } else { VMCNT0; }
            BARRIER;
            loadfrag(br, fa, fb);   // tile t+1
        }
        if (++br == 3) br = 0;
    }

    // ------------------------------------------------------------------
    // Epilogue. C/D layout: col = lane&15, row = (lane>>4)*4 + reg.
    // ------------------------------------------------------------------
    if (OUT_BF16) {
        __syncthreads();                       // all ds_reads done; LDS reusable
        char* tile = (char*)smem;              // [128][128] ushort, XOR-swizzled
        #pragma unroll
        for (int m = 0; m < 4; ++m) {
            #pragma unroll
            for (int n = 0; n < 4; ++n) {
                const int cc = wn * 64 + n * 16 + (lane & 15);
                const float bv = BIAS ? bias[col0 + cc] : 0.0f;
                #pragma unroll
                for (int r = 0; r < 4; ++r) {
                    const int rr = wm * 64 + m * 16 + (lane >> 4) * 4 + r;
                    float v = acc[m][n][r] + bv;
                    if (RELU) v = fmaxf(v, 0.0f);
                    const int byte = (rr * 256 + cc * 2) ^ (((rr >> 2) & 3) << 5);
                    *reinterpret_cast<unsigned short*>(tile + byte) = f2bf(v);
                }
            }
        }
        __syncthreads();
        const int cchunk = tid & 15;           // 16B (8-col) chunk
        const int rloc   = tid >> 4;           // 0..15
        #pragma unroll
        for (int p = 0; p < 8; ++p) {
            const int rr = p * 16 + rloc;
            const int byte = (rr * 256 + cchunk * 16) ^ (((rr >> 2) & 3) << 5);
            const uint4 v = *reinterpret_cast<const uint4*>(tile + byte);
            *reinterpret_cast<uint4*>(
                &((unsigned short*)Cout)[(size_t)(row0 + rr) * N + col0 + cchunk * 8]) = v;
        }
    } else {
        #pragma unroll
        for (int m = 0; m < 4; ++m) {
            #pragma unroll
            for (int n = 0; n < 4; ++n) {
                const int cg = col0 + wn * 64 + n * 16 + (lane & 15);
                const float bv = BIAS ? bias[cg] : 0.0f;
                #pragma unroll
                for (int r = 0; r < 4; ++r) {
                    const int rg = row0 + wm * 64 + m * 16 + (lane >> 4) * 4 + r;
                    float v = acc[m][n][r] + bv;
                    if (RELU) v = fmaxf(v, 0.0f);
                    ((float*)Cout)[(size_t)rg * N + cg] = v;
                }
            }
        }
    }
}

// ---------------------------------------------------------------------------
// Neighbor attention over fused qkv buffer [M][3072] (q|k|v), bf16.
// Writes compact attn output ab [M][1024] bf16. One block per (b,t).
// ---------------------------------------------------------------------------
__global__ __launch_bounds__(256) void attn_kernel(
    const unsigned short* __restrict__ qkv, const int* __restrict__ inxs,
    const float* __restrict__ radj, unsigned short* __restrict__ out)
{
    const int bt  = blockIdx.x;
    const int b   = bt >> 10;            // T = 1024
    const int tid = threadIdx.x;
    const float scale = 0.03125f;        // 1/sqrt(1024)

    __shared__ int   s_idx[K_];
    __shared__ float s_sc[K_];
    __shared__ float red[K_][4];

    if (tid < K_) s_idx[tid] = inxs[bt * K_ + tid];
    __syncthreads();

    const ushort4 qv = *reinterpret_cast<const ushort4*>(
        &qkv[(size_t)bt * 3072 + tid * 4]);
    const float qf[4] = { bf2f(qv.x), bf2f(qv.y), bf2f(qv.z), bf2f(qv.w) };

    float part[K_];
    #pragma unroll
    for (int k = 0; k < K_; ++k) {
        const size_t nb = (size_t)b * T_ + s_idx[k];
        const ushort4 kv = *reinterpret_cast<const ushort4*>(
            &qkv[nb * 3072 + 1024 + tid * 4]);
        part[k] = qf[0] * bf2f(kv.x) + qf[1] * bf2f(kv.y)
                + qf[2] * bf2f(kv.z) + qf[3] * bf2f(kv.w);
    }

    const int lane = tid & 63, wid = tid >> 6;
    #pragma unroll
    for (int k = 0; k < K_; ++k) {
        float v = part[k];
        #pragma unroll
        for (int off = 32; off; off >>= 1) v += __shfl_xor(v, off);
        if (lane == 0) red[k][wid] = v;
    }
    __syncthreads();
    if (tid < K_) {
        s_sc[tid] = (red[tid][0] + red[tid][1] + red[tid][2] + red[tid][3]) * scale
                    + radj[bt * K_ + tid];
    }
    __syncthreads();

    float m = s_sc[0];
    #pragma unroll
    for (int k = 1; k < K_; ++k) m = fmaxf(m, s_sc[k]);
    float w[K_], wsum = 0.f;
    #pragma unroll
    for (int k = 0; k < K_; ++k) { w[k] = expf(s_sc[k] - m); wsum += w[k]; }
    const float inv = 1.0f / wsum;

    float o[4] = {0.f, 0.f, 0.f, 0.f};
    #pragma unroll
    for (int k = 0; k < K_; ++k) {
        const size_t nb = (size_t)b * T_ + s_idx[k];
        const ushort4 vv = *reinterpret_cast<const ushort4*>(
            &qkv[nb * 3072 + 2048 + tid * 4]);
        const float wk = w[k] * inv;
        o[0] = fmaf(wk, bf2f(vv.x), o[0]);
        o[1] = fmaf(wk, bf2f(vv.y), o[1]);
        o[2] = fmaf(wk, bf2f(vv.z), o[2]);
        o[3] = fmaf(wk, bf2f(vv.w), o[3]);
    }
    ushort4 ov;
    ov.x = f2bf(o[0]); ov.y = f2bf(o[1]); ov.z = f2bf(o[2]); ov.w = f2bf(o[3]);
    *reinterpret_cast<ushort4*>(&out[(size_t)bt * C_ + tid * 4]) = ov;
}

// ---------------------------------------------------------------------------
// out = LayerNorm(a + (RELU ? relu(b) : b)) * g + beta; optional bf16 copy.
// ---------------------------------------------------------------------------
template <int RELU, int WB>
__global__ __launch_bounds__(256) void ln_residual_kernel(
    const float* __restrict__ a, const float* __restrict__ bb,
    const float* __restrict__ g, const float* __restrict__ beta,
    float* __restrict__ out, unsigned short* __restrict__ outb)
{
    const int bt  = blockIdx.x;
    const int tid = threadIdx.x;

    const float4 av = *reinterpret_cast<const float4*>(&a[(size_t)bt * C_ + tid * 4]);
    const float4 bv = *reinterpret_cast<const float4*>(&bb[(size_t)bt * C_ + tid * 4]);
    float4 s;
    s.x = av.x + (RELU ? fmaxf(bv.x, 0.f) : bv.x);
    s.y = av.y + (RELU ? fmaxf(bv.y, 0.f) : bv.y);
    s.z = av.z + (RELU ? fmaxf(bv.z, 0.f) : bv.z);
    s.w = av.w + (RELU ? fmaxf(bv.w, 0.f) : bv.w);

    float sum = s.x + s.y + s.z + s.w;
    float sq  = s.x * s.x + s.y * s.y + s.z * s.z + s.w * s.w;

    const int lane = tid & 63, wid = tid >> 6;
    __shared__ float rs[4], rq[4];
    #pragma unroll
    for (int off = 32; off; off >>= 1) {
        sum += __shfl_xor(sum, off);
        sq  += __shfl_xor(sq,  off);
    }
    if (lane == 0) { rs[wid] = sum; rq[wid] = sq; }
    __syncthreads();
    sum = rs[0] + rs[1] + rs[2] + rs[3];
    sq  = rq[0] + rq[1] + rq[2] + rq[3];

    const float mu  = sum * (1.0f / C_);
    const float var = sq * (1.0f / C_) - mu * mu;
    const float r   = rsqrtf(var + EPS_);

    const float4 gv = *reinterpret_cast<const float4*>(&g[tid * 4]);
    const float4 be = *reinterpret_cast<const float4*>(&beta[tid * 4]);
    float4 o;
    o.x = (s.x - mu) * r * gv.x + be.x;
    o.y = (s.y - mu) * r * gv.y + be.y;
    o.z = (s.z - mu) * r * gv.z + be.z;
    o.w = (s.w - mu) * r * gv.w + be.w;
    *reinterpret_cast<float4*>(&out[(size_t)bt * C_ + tid * 4]) = o;
    if (WB) {
        ushort4 ob;
        ob.x = f2bf(o.x); ob.y = f2bf(o.y); ob.z = f2bf(o.z); ob.w = f2bf(o.w);
        *reinterpret_cast<ushort4*>(&outb[(size_t)bt * C_ + tid * 4]) = ob;
    }
}

// ---------------------------------------------------------------------------
extern "C" void kernel_launch(void* const* d_in, const int* in_sizes, int n_in,
                              void* d_out, int out_size, void* d_ws, size_t ws_size,
                              hipStream_t stream)
{
    const float* x     = (const float*)d_in[0];
    const float* radj  = (const float*)d_in[1];
    const int*   inxs  = (const int*)  d_in[2];
    const float* Wq    = (const float*)d_in[3];
    const float* Wk    = (const float*)d_in[4];
    const float* Wv    = (const float*)d_in[5];
    const float* Wo    = (const float*)d_in[6];
    const float* ln1_g = (const float*)d_in[7];
    const float* ln1_b = (const float*)d_in[8];
    const float* W1    = (const float*)d_in[9];
    const float* b1    = (const float*)d_in[10];
    const float* W2    = (const float*)d_in[11];
    const float* b2    = (const float*)d_in[12];
    const float* ln2_g = (const float*)d_in[13];
    const float* ln2_b = (const float*)d_in[14];
    float* out = (float*)d_out;

    char* wsb = (char*)d_ws;
    const size_t MB = 1 << 20;
    // Weights (bf16, pre-transposed to N x K):
    unsigned short* WqkvT = (unsigned short*)(wsb + 0 * MB);   // 3072x1024, 6 MB
    unsigned short* WoT   = (unsigned short*)(wsb + 6 * MB);   // 1024x1024, 2 MB
    unsigned short* W1T   = (unsigned short*)(wsb + 8 * MB);   // 1536x1024, 3 MB
    unsigned short* W2T   = (unsigned short*)(wsb + 11 * MB);  // 1024x1536, 3 MB
    // Activations (aliased timeline; ws >= 256 MB):
    unsigned short* xb  = (unsigned short*)(wsb + 16 * MB);    // 32 MB; hop state
    unsigned short* hb  = xb;                                  // hop1 Wo out (bf16)
    unsigned short* qkv = (unsigned short*)(wsb + 48 * MB);    // 96 MB (48..144)
    unsigned short* ab  = (unsigned short*)(wsb + 144 * MB);   // 32 MB (144..176)
    float*          h2  = (float*)(wsb + 48 * MB);             // 64 MB (over dead qkv)
    float*          y   = (float*)(wsb + 112 * MB);            // 64 MB (112..176)
    unsigned short* yb  = (unsigned short*)(wsb + 176 * MB);   // 32 MB (176..208)
    unsigned short* hid = (unsigned short*)(wsb + 208 * MB);   // 48 MB (208..256)
    float*          f   = (float*)(wsb + 48 * MB);             // 64 MB (over dead h2)

    const int M = B_ * T_;
    const dim3 blk(256);
    const dim3 gQKV(3 * C_ / 128, M / 128);   // 24 x 128 = 3072 blocks
    const dim3 gC(C_ / 128, M / 128);         // 8 x 128 = 1024
    const dim3 gH(H_ / 128, M / 128);         // 12 x 128 = 1536

    // --- weight + input conversion ---
    wtrans_kernel<<<dim3(32, 32), blk, 0, stream>>>(Wq, WqkvT,                C_, C_);
    wtrans_kernel<<<dim3(32, 32), blk, 0, stream>>>(Wk, WqkvT + 1024 * 1024,  C_, C_);
    wtrans_kernel<<<dim3(32, 32), blk, 0, stream>>>(Wv, WqkvT + 2048 * 1024,  C_, C_);
    wtrans_kernel<<<dim3(32, 32), blk, 0, stream>>>(Wo, WoT, C_, C_);
    wtrans_kernel<<<dim3(48, 32), blk, 0, stream>>>(W1, W1T, C_, H_);   // -> H x C
    wtrans_kernel<<<dim3(32, 48), blk, 0, stream>>>(W2, W2T, H_, C_);   // -> C x H
    f2bf_kernel<<<dim3((size_t)M * C_ / 1024), blk, 0, stream>>>(x, xb);

    // --- hops ---
    for (int hop = 0; hop < TNEI_; ++hop) {
        const unsigned short* hin = (hop == 0) ? xb : hb;
        gemm_bt_kernel<1, 0, 0><<<gQKV, blk, 0, stream>>>(hin, WqkvT, nullptr, qkv,
                                                          M, 3 * C_, C_);
        attn_kernel<<<dim3(M), blk, 0, stream>>>(qkv, inxs, radj, ab);
        if (hop == 0)
            gemm_bt_kernel<1, 0, 0><<<gC, blk, 0, stream>>>(ab, WoT, nullptr, hb,
                                                            M, C_, C_);
        else
            gemm_bt_kernel<0, 0, 0><<<gC, blk, 0, stream>>>(ab, WoT, nullptr, h2,
                                                            M, C_, C_);
    }

    // --- residual + LN1 (f32 y and bf16 yb) ---
    ln_residual_kernel<1, 1><<<dim3(M), blk, 0, stream>>>(x, h2, ln1_g, ln1_b, y, yb);
    // --- FFN ---
    gemm_bt_kernel<1, 1, 1><<<gH, blk, 0, stream>>>(yb,  W1T, b1, hid, M, H_, C_);
    gemm_bt_kernel<0, 1, 0><<<gC, blk, 0, stream>>>(hid, W2T, b2, f,   M, C_, H_);
    // --- residual + LN2 ---
    ln_residual_kernel<0, 0><<<dim3(M), blk, 0, stream>>>(y, f, ln2_g, ln2_b, out, nullptr);
}

// Round 6
// 789.644 us; speedup vs baseline: 5.9843x; 1.0154x over previous
//
#include <hip/hip_runtime.h>
#include <hip/hip_bf16.h>
#include <cstddef>
#include <cstdint>

#define B_    16
#define T_    1024
#define C_    1024
#define K_    8
#define H_    1536
#define TNEI_ 2
static constexpr float EPS_ = 1e-5f;

typedef __attribute__((ext_vector_type(8))) short bf16x8;
typedef __attribute__((ext_vector_type(4))) float f32x4;

__device__ __forceinline__ float bf2f(unsigned short u) {
    return __uint_as_float(((unsigned)u) << 16);
}
__device__ __forceinline__ unsigned short f2bf(float f) {
    __hip_bfloat16 h = __float2bfloat16(f);
    union { __hip_bfloat16 h; unsigned short u; } cvt;
    cvt.h = h;
    return cvt.u;
}

__device__ __forceinline__ void gload_lds16(const void* g, void* l) {
    __builtin_amdgcn_global_load_lds(
        (const __attribute__((address_space(1))) void*)g,
        (__attribute__((address_space(3))) void*)l,
        16, 0, 0);
}

#define VMCNT0 asm volatile("s_waitcnt vmcnt(0)" ::: "memory")
#define VMCNT4 asm volatile("s_waitcnt vmcnt(4)" ::: "memory")
// raw barrier + compiler fences: no memory op may be hoisted across
#define BARRIER do {                                   \
    __builtin_amdgcn_sched_barrier(0);                 \
    __builtin_amdgcn_s_barrier();                      \
    asm volatile("" ::: "memory");                     \
    __builtin_amdgcn_sched_barrier(0);                 \
} while (0)

// ---------------------------------------------------------------------------
// f32 -> bf16 elementwise (4 per thread)
// ---------------------------------------------------------------------------
__global__ __launch_bounds__(256) void f2bf_kernel(
    const float* __restrict__ in, unsigned short* __restrict__ out)
{
    const size_t i = (size_t)blockIdx.x * 256 + threadIdx.x;
    const float4 v = *reinterpret_cast<const float4*>(&in[i * 4]);
    ushort4 o;
    o.x = f2bf(v.x); o.y = f2bf(v.y); o.z = f2bf(v.z); o.w = f2bf(v.w);
    *reinterpret_cast<ushort4*>(&out[i * 4]) = o;
}

// ---------------------------------------------------------------------------
// Transpose + convert: W (R x Cc, f32) -> WT (Cc x R, bf16)
// ---------------------------------------------------------------------------
__global__ __launch_bounds__(256) void wtrans_kernel(
    const float* __restrict__ W, unsigned short* __restrict__ WT, int R, int Cc)
{
    __shared__ float t[32][33];
    const int c0 = blockIdx.x * 32, r0 = blockIdx.y * 32;
    const int tx = threadIdx.x & 31, ty = threadIdx.x >> 5;  // 32 x 8
    #pragma unroll
    for (int i = 0; i < 4; ++i)
        t[ty + 8 * i][tx] = W[(size_t)(r0 + ty + 8 * i) * Cc + c0 + tx];
    __syncthreads();
    #pragma unroll
    for (int i = 0; i < 4; ++i)
        WT[(size_t)(c0 + ty + 8 * i) * R + r0 + tx] = f2bf(t[tx][ty + 8 * i]);
}

// ---------------------------------------------------------------------------
// bf16 MFMA GEMM: 256x256 tile, triple-buffered, distance-2 prefetch,
// counted vmcnt (same verified sync skeleton as R5, scaled geometry).
//   C[M,N] = A[M,K] @ Bt[N,K]^T (+bias)(+relu)
// BK=32, 512 threads = 8 waves (2M x 4N), 128x64 per wave (8x4 frags).
//
// Phase t:  stage(t+2) -> buf[(t+2)%3]          (4 gload_lds / thread)
//           mfma(tile t) from regs               (auto-lgkm drains prev reads)
//           vmcnt(4)  -> own tile-(t+1) loads done (t+2 stays in flight)
//           s_barrier -> ALL waves' tile-(t+1) loads confirmed
//           loadfrag(t+1) -> regs                (reads strictly after barrier)
// WAR: stage(t+2) reuses buf of tile t-1 whose ds_reads were consumed by
// mfma(t-1) before barrier(t-1) in every wave. RAW: per-wave vmcnt before
// the barrier + reads after it.
// T2 swizzle: LDS[R][S] holds global k-chunk S ^ ((R>>1)&3); applied on the
// gload *source* (dest linear, rule #21) and on the ds_read slot.
// Requires (gridDim.x*gridDim.y)%8==0, K%64==0, M%256==0, N%256==0.
// ---------------------------------------------------------------------------
template <int OUT_BF16, int BIAS, int RELU>
__global__ __launch_bounds__(512, 2) void gemm_bt_kernel(
    const unsigned short* __restrict__ A, const unsigned short* __restrict__ Bt,
    const float* __restrict__ bias, void* __restrict__ Cout,
    int M, int N, int K)
{
    constexpr int BK = 32;
    // 3 bufs x (A 256x32 + B 256x32) ushort = 3 x 32 KB = 96 KB
    __shared__ unsigned short smem[3 * 16384];

    const int tid  = threadIdx.x;
    const int lane = tid & 63;
    const int wid  = tid >> 6;              // 0..7
    const int wm   = wid >> 2, wn = wid & 3;

    // T1: chunked XCD swizzle (bijective; nwg % 8 == 0 for all our grids)
    const int nwg  = gridDim.x * gridDim.y;
    int bidl = blockIdx.y * gridDim.x + blockIdx.x;
    bidl = (bidl & 7) * (nwg >> 3) + (bidl >> 3);
    const int bx = bidl % gridDim.x;
    const int by = bidl / gridDim.x;
    const int row0 = by * 256;
    const int col0 = bx * 256;

    const int NT = K >> 5;                    // 32 (K=1024) or 48 (K=1536), even

    // staging: 4 gloads/thread/tile; source k-chunk pre-swizzled (T2 inverse)
    const int sub = lane >> 2;                // row within 16-row chunk-group
    const int kk  = (((lane & 3) ^ ((lane >> 3) & 3))) * 8;

    f32x4 acc[8][4] = {};

    auto stage = [&](int kt, int bufi) {
        unsigned short* As = smem + bufi * 16384;
        unsigned short* Bs = As + 8192;
        #pragma unroll
        for (int i = 0; i < 2; ++i) {
            const int cg = i * 8 + wid;               // 0..15, 16 rows each
            const int r = cg * 16 + sub;              // 0..255
            gload_lds16(&A[(size_t)(row0 + r) * K + kt + kk], &As[cg * 512]);
        }
        #pragma unroll
        for (int i = 0; i < 2; ++i) {
            const int cg = i * 8 + wid;
            const int r = cg * 16 + sub;
            gload_lds16(&Bt[(size_t)(col0 + r) * K + kt + kk], &Bs[cg * 512]);
        }
    };

    const int slot = ((lane >> 4) ^ ((lane >> 1) & 3)) * 8;  // T2 read swizzle
    auto loadfrag = [&](int bufi, bf16x8* a, bf16x8* b) {
        const unsigned short* As = smem + bufi * 16384;
        const unsigned short* Bs = As + 8192;
        #pragma unroll
        for (int m = 0; m < 8; ++m) {
            const int r = wm * 128 + m * 16 + (lane & 15);
            a[m] = *reinterpret_cast<const bf16x8*>(&As[r * 32 + slot]);
        }
        #pragma unroll
        for (int n = 0; n < 4; ++n) {
            const int c = wn * 64 + n * 16 + (lane & 15);
            b[n] = *reinterpret_cast<const bf16x8*>(&Bs[c * 32 + slot]);
        }
    };

    auto mfma32 = [&](const bf16x8* a, const bf16x8* b) {
        __builtin_amdgcn_s_setprio(1);
        #pragma unroll
        for (int m = 0; m < 8; ++m)
            #pragma unroll
            for (int n = 0; n < 4; ++n)
                acc[m][n] = __builtin_amdgcn_mfma_f32_16x16x32_bf16(
                    a[m], b[n], acc[m][n], 0, 0, 0);
        __builtin_amdgcn_s_setprio(0);
    };

    bf16x8 fa[8], fb[4];

    // prologue: stage tiles 0,1; confirm tile 0 (all waves) before first read
    stage(0, 0);
    stage(BK, 1);
    VMCNT4;                 // own tile-0 loads done; tile 1 in flight
    BARRIER;                // every wave's tile-0 loads confirmed
    loadfrag(0, fa, fb);

    int bs = 2, br = 1;     // stage buf = (t+2)%3, read buf = (t+1)%3
    for (int t = 0; t < NT; ++t) {
        if (t + 2 < NT) stage((t + 2) * BK, bs);
        if (++bs == 3) bs = 0;
        mfma32(fa, fb);     // consumes loadfrag(t); auto-lgkm drains ds_reads
        if (t + 1 < NT) {
            if (t + 2 < NT) { VMCNT4; } else { VMCNT0; }
            BARRIER;
            loadfrag(br, fa, fb);   // tile t+1
        }
        if (++br == 3) br = 0;
    }

    // ------------------------------------------------------------------
    // Epilogue. C/D frag layout: col = lane&15, row = (lane>>4)*4 + reg.
    // bf16 path: two half-passes via [128][256] ushort LDS tile (64 KB),
    // XOR-swizzled; pass p covers frag rows m = p*4 .. p*4+3.
    // lrow = wm*64 + (m&3)*16 + (lane>>4)*4 + r; grow = (lrow>>6)*128 +
    // p*64 + (lrow&63).
    // ------------------------------------------------------------------
    if (OUT_BF16) {
        char* tile = (char*)smem;
        #pragma unroll
        for (int p = 0; p < 2; ++p) {
            __syncthreads();               // prior reads (K-loop / pass) done
            #pragma unroll
            for (int m4 = 0; m4 < 4; ++m4) {
                const int m = p * 4 + m4;
                #pragma unroll
                for (int n = 0; n < 4; ++n) {
                    const int cc = wn * 64 + n * 16 + (lane & 15);
                    const float bv = BIAS ? bias[col0 + cc] : 0.0f;
                    #pragma unroll
                    for (int r = 0; r < 4; ++r) {
                        const int lrow = wm * 64 + m4 * 16 + (lane >> 4) * 4 + r;
                        float v = acc[m][n][r] + bv;
                        if (RELU) v = fmaxf(v, 0.0f);
                        const int byte = (lrow * 512 + cc * 2) ^ (((lrow >> 2) & 3) << 5);
                        *reinterpret_cast<unsigned short*>(tile + byte) = f2bf(v);
                    }
                }
            }
            __syncthreads();
            const int cchunk = tid & 31;        // 16B (8-col) chunk, 32/row
            const int rbase  = tid >> 5;        // 0..15
            #pragma unroll
            for (int it = 0; it < 8; ++it) {
                const int lr = it * 16 + rbase;
                const int byte = (lr * 512 + cchunk * 16) ^ (((lr >> 2) & 3) << 5);
                const uint4 v = *reinterpret_cast<const uint4*>(tile + byte);
                const int grow = row0 + (lr >> 6) * 128 + p * 64 + (lr & 63);
                *reinterpret_cast<uint4*>(
                    &((unsigned short*)Cout)[(size_t)grow * N + col0 + cchunk * 8]) = v;
            }
        }
    } else {
        #pragma unroll
        for (int m = 0; m < 8; ++m) {
            #pragma unroll
            for (int n = 0; n < 4; ++n) {
                const int cg = col0 + wn * 64 + n * 16 + (lane & 15);
                const float bv = BIAS ? bias[cg] : 0.0f;
                #pragma unroll
                for (int r = 0; r < 4; ++r) {
                    const int rg = row0 + wm * 128 + m * 16 + (lane >> 4) * 4 + r;
                    float v = acc[m][n][r] + bv;
                    if (RELU) v = fmaxf(v, 0.0f);
                    ((float*)Cout)[(size_t)rg * N + cg] = v;
                }
            }
        }
    }
}

// ---------------------------------------------------------------------------
// Neighbor attention over fused qkv buffer [M][3072] (q|k|v), bf16.
// Writes compact attn output ab [M][1024] bf16. One block per (b,t).
// ---------------------------------------------------------------------------
__global__ __launch_bounds__(256) void attn_kernel(
    const unsigned short* __restrict__ qkv, const int* __restrict__ inxs,
    const float* __restrict__ radj, unsigned short* __restrict__ out)
{
    const int bt  = blockIdx.x;
    const int b   = bt >> 10;            // T = 1024
    const int tid = threadIdx.x;
    const float scale = 0.03125f;        // 1/sqrt(1024)

    __shared__ int   s_idx[K_];
    __shared__ float s_sc[K_];
    __shared__ float red[K_][4];

    if (tid < K_) s_idx[tid] = inxs[bt * K_ + tid];
    __syncthreads();

    const ushort4 qv = *reinterpret_cast<const ushort4*>(
        &qkv[(size_t)bt * 3072 + tid * 4]);
    const float qf[4] = { bf2f(qv.x), bf2f(qv.y), bf2f(qv.z), bf2f(qv.w) };

    float part[K_];
    #pragma unroll
    for (int k = 0; k < K_; ++k) {
        const size_t nb = (size_t)b * T_ + s_idx[k];
        const ushort4 kv = *reinterpret_cast<const ushort4*>(
            &qkv[nb * 3072 + 1024 + tid * 4]);
        part[k] = qf[0] * bf2f(kv.x) + qf[1] * bf2f(kv.y)
                + qf[2] * bf2f(kv.z) + qf[3] * bf2f(kv.w);
    }

    const int lane = tid & 63, wid = tid >> 6;
    #pragma unroll
    for (int k = 0; k < K_; ++k) {
        float v = part[k];
        #pragma unroll
        for (int off = 32; off; off >>= 1) v += __shfl_xor(v, off);
        if (lane == 0) red[k][wid] = v;
    }
    __syncthreads();
    if (tid < K_) {
        s_sc[tid] = (red[tid][0] + red[tid][1] + red[tid][2] + red[tid][3]) * scale
                    + radj[bt * K_ + tid];
    }
    __syncthreads();

    float m = s_sc[0];
    #pragma unroll
    for (int k = 1; k < K_; ++k) m = fmaxf(m, s_sc[k]);
    float w[K_], wsum = 0.f;
    #pragma unroll
    for (int k = 0; k < K_; ++k) { w[k] = expf(s_sc[k] - m); wsum += w[k]; }
    const float inv = 1.0f / wsum;

    float o[4] = {0.f, 0.f, 0.f, 0.f};
    #pragma unroll
    for (int k = 0; k < K_; ++k) {
        const size_t nb = (size_t)b * T_ + s_idx[k];
        const ushort4 vv = *reinterpret_cast<const ushort4*>(
            &qkv[nb * 3072 + 2048 + tid * 4]);
        const float wk = w[k] * inv;
        o[0] = fmaf(wk, bf2f(vv.x), o[0]);
        o[1] = fmaf(wk, bf2f(vv.y), o[1]);
        o[2] = fmaf(wk, bf2f(vv.z), o[2]);
        o[3] = fmaf(wk, bf2f(vv.w), o[3]);
    }
    ushort4 ov;
    ov.x = f2bf(o[0]); ov.y = f2bf(o[1]); ov.z = f2bf(o[2]); ov.w = f2bf(o[3]);
    *reinterpret_cast<ushort4*>(&out[(size_t)bt * C_ + tid * 4]) = ov;
}

// ---------------------------------------------------------------------------
// out = LayerNorm(a + (RELU ? relu(b) : b)) * g + beta; optional bf16 copy.
// ---------------------------------------------------------------------------
template <int RELU, int WB>
__global__ __launch_bounds__(256) void ln_residual_kernel(
    const float* __restrict__ a, const float* __restrict__ bb,
    const float* __restrict__ g, const float* __restrict__ beta,
    float* __restrict__ out, unsigned short* __restrict__ outb)
{
    const int bt  = blockIdx.x;
    const int tid = threadIdx.x;

    const float4 av = *reinterpret_cast<const float4*>(&a[(size_t)bt * C_ + tid * 4]);
    const float4 bv = *reinterpret_cast<const float4*>(&bb[(size_t)bt * C_ + tid * 4]);
    float4 s;
    s.x = av.x + (RELU ? fmaxf(bv.x, 0.f) : bv.x);
    s.y = av.y + (RELU ? fmaxf(bv.y, 0.f) : bv.y);
    s.z = av.z + (RELU ? fmaxf(bv.z, 0.f) : bv.z);
    s.w = av.w + (RELU ? fmaxf(bv.w, 0.f) : bv.w);

    float sum = s.x + s.y + s.z + s.w;
    float sq  = s.x * s.x + s.y * s.y + s.z * s.z + s.w * s.w;

    const int lane = tid & 63, wid = tid >> 6;
    __shared__ float rs[4], rq[4];
    #pragma unroll
    for (int off = 32; off; off >>= 1) {
        sum += __shfl_xor(sum, off);
        sq  += __shfl_xor(sq,  off);
    }
    if (lane == 0) { rs[wid] = sum; rq[wid] = sq; }
    __syncthreads();
    sum = rs[0] + rs[1] + rs[2] + rs[3];
    sq  = rq[0] + rq[1] + rq[2] + rq[3];

    const float mu  = sum * (1.0f / C_);
    const float var = sq * (1.0f / C_) - mu * mu;
    const float r   = rsqrtf(var + EPS_);

    const float4 gv = *reinterpret_cast<const float4*>(&g[tid * 4]);
    const float4 be = *reinterpret_cast<const float4*>(&beta[tid * 4]);
    float4 o;
    o.x = (s.x - mu) * r * gv.x + be.x;
    o.y = (s.y - mu) * r * gv.y + be.y;
    o.z = (s.z - mu) * r * gv.z + be.z;
    o.w = (s.w - mu) * r * gv.w + be.w;
    *reinterpret_cast<float4*>(&out[(size_t)bt * C_ + tid * 4]) = o;
    if (WB) {
        ushort4 ob;
        ob.x = f2bf(o.x); ob.y = f2bf(o.y); ob.z = f2bf(o.z); ob.w = f2bf(o.w);
        *reinterpret_cast<ushort4*>(&outb[(size_t)bt * C_ + tid * 4]) = ob;
    }
}

// ---------------------------------------------------------------------------
extern "C" void kernel_launch(void* const* d_in, const int* in_sizes, int n_in,
                              void* d_out, int out_size, void* d_ws, size_t ws_size,
                              hipStream_t stream)
{
    const float* x     = (const float*)d_in[0];
    const float* radj  = (const float*)d_in[1];
    const int*   inxs  = (const int*)  d_in[2];
    const float* Wq    = (const float*)d_in[3];
    const float* Wk    = (const float*)d_in[4];
    const float* Wv    = (const float*)d_in[5];
    const float* Wo    = (const float*)d_in[6];
    const float* ln1_g = (const float*)d_in[7];
    const float* ln1_b = (const float*)d_in[8];
    const float* W1    = (const float*)d_in[9];
    const float* b1    = (const float*)d_in[10];
    const float* W2    = (const float*)d_in[11];
    const float* b2    = (const float*)d_in[12];
    const float* ln2_g = (const float*)d_in[13];
    const float* ln2_b = (const float*)d_in[14];
    float* out = (float*)d_out;

    char* wsb = (char*)d_ws;
    const size_t MB = 1 << 20;
    // Weights (bf16, pre-transposed to N x K):
    unsigned short* WqkvT = (unsigned short*)(wsb + 0 * MB);   // 3072x1024, 6 MB
    unsigned short* WoT   = (unsigned short*)(wsb + 6 * MB);   // 1024x1024, 2 MB
    unsigned short* W1T   = (unsigned short*)(wsb + 8 * MB);   // 1536x1024, 3 MB
    unsigned short* W2T   = (unsigned short*)(wsb + 11 * MB);  // 1024x1536, 3 MB
    // Activations (aliased timeline; ws >= 256 MB):
    unsigned short* xb  = (unsigned short*)(wsb + 16 * MB);    // 32 MB; hop state
    unsigned short* hb  = xb;                                  // hop1 Wo out (bf16)
    unsigned short* qkv = (unsigned short*)(wsb + 48 * MB);    // 96 MB (48..144)
    unsigned short* ab  = (unsigned short*)(wsb + 144 * MB);   // 32 MB (144..176)
    float*          h2  = (float*)(wsb + 48 * MB);             // 64 MB (over dead qkv)
    float*          y   = (float*)(wsb + 112 * MB);            // 64 MB (112..176)
    unsigned short* yb  = (unsigned short*)(wsb + 176 * MB);   // 32 MB (176..208)
    unsigned short* hid = (unsigned short*)(wsb + 208 * MB);   // 48 MB (208..256)
    float*          f   = (float*)(wsb + 48 * MB);             // 64 MB (over dead h2)

    const int M = B_ * T_;
    const dim3 blk(256);
    const dim3 blkG(512);
    const dim3 gQKV(3 * C_ / 256, M / 256);   // 12 x 64 = 768 blocks
    const dim3 gC(C_ / 256, M / 256);         // 4 x 64 = 256
    const dim3 gH(H_ / 256, M / 256);         // 6 x 64 = 384

    // --- weight + input conversion ---
    wtrans_kernel<<<dim3(32, 32), blk, 0, stream>>>(Wq, WqkvT,                C_, C_);
    wtrans_kernel<<<dim3(32, 32), blk, 0, stream>>>(Wk, WqkvT + 1024 * 1024,  C_, C_);
    wtrans_kernel<<<dim3(32, 32), blk, 0, stream>>>(Wv, WqkvT + 2048 * 1024,  C_, C_);
    wtrans_kernel<<<dim3(32, 32), blk, 0, stream>>>(Wo, WoT, C_, C_);
    wtrans_kernel<<<dim3(48, 32), blk, 0, stream>>>(W1, W1T, C_, H_);   // -> H x C
    wtrans_kernel<<<dim3(32, 48), blk, 0, stream>>>(W2, W2T, H_, C_);   // -> C x H
    f2bf_kernel<<<dim3((size_t)M * C_ / 1024), blk, 0, stream>>>(x, xb);

    // --- hops ---
    for (int hop = 0; hop < TNEI_; ++hop) {
        const unsigned short* hin = (hop == 0) ? xb : hb;
        gemm_bt_kernel<1, 0, 0><<<gQKV, blkG, 0, stream>>>(hin, WqkvT, nullptr, qkv,
                                                           M, 3 * C_, C_);
        attn_kernel<<<dim3(M), blk, 0, stream>>>(qkv, inxs, radj, ab);
        if (hop == 0)
            gemm_bt_kernel<1, 0, 0><<<gC, blkG, 0, stream>>>(ab, WoT, nullptr, hb,
                                                             M, C_, C_);
        else
            gemm_bt_kernel<0, 0, 0><<<gC, blkG, 0, stream>>>(ab, WoT, nullptr, h2,
                                                             M, C_, C_);
    }

    // --- residual + LN1 (f32 y and bf16 yb) ---
    ln_residual_kernel<1, 1><<<dim3(M), blk, 0, stream>>>(x, h2, ln1_g, ln1_b, y, yb);
    // --- FFN ---
    gemm_bt_kernel<1, 1, 1><<<gH, blkG, 0, stream>>>(yb,  W1T, b1, hid, M, H_, C_);
    gemm_bt_kernel<0, 1, 0><<<gC, blkG, 0, stream>>>(hid, W2T, b2, f,   M, C_, H_);
    // --- residual + LN2 ---
    ln_residual_kernel<0, 0><<<dim3(M), blk, 0, stream>>>(y, f, ln2_g, ln2_b, out, nullptr);
}

// Round 7
// 764.759 us; speedup vs baseline: 6.1790x; 1.0325x over previous
//
#include <hip/hip_runtime.h>
#include <hip/hip_bf16.h>
#include <cstddef>
#include <cstdint>

#define B_    16
#define T_    1024
#define C_    1024
#define K_    8
#define H_    1536
#define TNEI_ 2
static constexpr float EPS_ = 1e-5f;

typedef __attribute__((ext_vector_type(8))) short bf16x8;
typedef __attribute__((ext_vector_type(4))) float f32x4;

__device__ __forceinline__ float bf2f(unsigned short u) {
    return __uint_as_float(((unsigned)u) << 16);
}
__device__ __forceinline__ unsigned short f2bf(float f) {
    __hip_bfloat16 h = __float2bfloat16(f);
    union { __hip_bfloat16 h; unsigned short u; } cvt;
    cvt.h = h;
    return cvt.u;
}

__device__ __forceinline__ void gload_lds16(const void* g, void* l) {
    __builtin_amdgcn_global_load_lds(
        (const __attribute__((address_space(1))) void*)g,
        (__attribute__((address_space(3))) void*)l,
        16, 0, 0);
}

#define VMCNT0 asm volatile("s_waitcnt vmcnt(0)" ::: "memory")
#define VMCNT4 asm volatile("s_waitcnt vmcnt(4)" ::: "memory")
// raw barrier + compiler fences: no memory op may be hoisted across
#define BARRIER do {                                   \
    __builtin_amdgcn_sched_barrier(0);                 \
    __builtin_amdgcn_s_barrier();                      \
    asm volatile("" ::: "memory");                     \
    __builtin_amdgcn_sched_barrier(0);                 \
} while (0)

// ---------------------------------------------------------------------------
// f32 -> bf16 elementwise (4 per thread)
// ---------------------------------------------------------------------------
__global__ __launch_bounds__(256) void f2bf_kernel(
    const float* __restrict__ in, unsigned short* __restrict__ out)
{
    const size_t i = (size_t)blockIdx.x * 256 + threadIdx.x;
    const float4 v = *reinterpret_cast<const float4*>(&in[i * 4]);
    ushort4 o;
    o.x = f2bf(v.x); o.y = f2bf(v.y); o.z = f2bf(v.z); o.w = f2bf(v.w);
    *reinterpret_cast<ushort4*>(&out[i * 4]) = o;
}

// ---------------------------------------------------------------------------
// Transpose + convert: W (R x Cc, f32) -> WT (Cc x R, bf16)
// ---------------------------------------------------------------------------
__global__ __launch_bounds__(256) void wtrans_kernel(
    const float* __restrict__ W, unsigned short* __restrict__ WT, int R, int Cc)
{
    __shared__ float t[32][33];
    const int c0 = blockIdx.x * 32, r0 = blockIdx.y * 32;
    const int tx = threadIdx.x & 31, ty = threadIdx.x >> 5;  // 32 x 8
    #pragma unroll
    for (int i = 0; i < 4; ++i)
        t[ty + 8 * i][tx] = W[(size_t)(r0 + ty + 8 * i) * Cc + c0 + tx];
    __syncthreads();
    #pragma unroll
    for (int i = 0; i < 4; ++i)
        WT[(size_t)(c0 + ty + 8 * i) * R + r0 + tx] = f2bf(t[tx][ty + 8 * i]);
}

// ---------------------------------------------------------------------------
// bf16 MFMA GEMM: 256x256 tile, triple-buffered, distance-2 prefetch,
// counted vmcnt (verified sync skeleton from R5/R6).
//   C[M,N] = A[M,K] @ Bt[N,K]^T (+bias)(+relu)
// BK=32, 512 threads = 8 waves (2M x 4N), 128x64 per wave (8x4 frags).
// ---------------------------------------------------------------------------
template <int OUT_BF16, int BIAS, int RELU>
__global__ __launch_bounds__(512, 2) void gemm_bt_kernel(
    const unsigned short* __restrict__ A, const unsigned short* __restrict__ Bt,
    const float* __restrict__ bias, void* __restrict__ Cout,
    int M, int N, int K)
{
    constexpr int BK = 32;
    // 3 bufs x (A 256x32 + B 256x32) ushort = 3 x 32 KB = 96 KB
    __shared__ unsigned short smem[3 * 16384];

    const int tid  = threadIdx.x;
    const int lane = tid & 63;
    const int wid  = tid >> 6;              // 0..7
    const int wm   = wid >> 2, wn = wid & 3;

    // T1: chunked XCD swizzle (bijective; nwg % 8 == 0 for all our grids)
    const int nwg  = gridDim.x * gridDim.y;
    int bidl = blockIdx.y * gridDim.x + blockIdx.x;
    bidl = (bidl & 7) * (nwg >> 3) + (bidl >> 3);
    const int bx = bidl % gridDim.x;
    const int by = bidl / gridDim.x;
    const int row0 = by * 256;
    const int col0 = bx * 256;

    const int NT = K >> 5;                    // 32 (K=1024) or 48 (K=1536), even

    // staging: 4 gloads/thread/tile; source k-chunk pre-swizzled (T2 inverse)
    const int sub = lane >> 2;                // row within 16-row chunk-group
    const int kk  = (((lane & 3) ^ ((lane >> 3) & 3))) * 8;

    f32x4 acc[8][4] = {};

    auto stage = [&](int kt, int bufi) {
        unsigned short* As = smem + bufi * 16384;
        unsigned short* Bs = As + 8192;
        #pragma unroll
        for (int i = 0; i < 2; ++i) {
            const int cg = i * 8 + wid;               // 0..15, 16 rows each
            const int r = cg * 16 + sub;              // 0..255
            gload_lds16(&A[(size_t)(row0 + r) * K + kt + kk], &As[cg * 512]);
        }
        #pragma unroll
        for (int i = 0; i < 2; ++i) {
            const int cg = i * 8 + wid;
            const int r = cg * 16 + sub;
            gload_lds16(&Bt[(size_t)(col0 + r) * K + kt + kk], &Bs[cg * 512]);
        }
    };

    const int slot = ((lane >> 4) ^ ((lane >> 1) & 3)) * 8;  // T2 read swizzle
    auto loadfrag = [&](int bufi, bf16x8* a, bf16x8* b) {
        const unsigned short* As = smem + bufi * 16384;
        const unsigned short* Bs = As + 8192;
        #pragma unroll
        for (int m = 0; m < 8; ++m) {
            const int r = wm * 128 + m * 16 + (lane & 15);
            a[m] = *reinterpret_cast<const bf16x8*>(&As[r * 32 + slot]);
        }
        #pragma unroll
        for (int n = 0; n < 4; ++n) {
            const int c = wn * 64 + n * 16 + (lane & 15);
            b[n] = *reinterpret_cast<const bf16x8*>(&Bs[c * 32 + slot]);
        }
    };

    auto mfma32 = [&](const bf16x8* a, const bf16x8* b) {
        __builtin_amdgcn_s_setprio(1);
        #pragma unroll
        for (int m = 0; m < 8; ++m)
            #pragma unroll
            for (int n = 0; n < 4; ++n)
                acc[m][n] = __builtin_amdgcn_mfma_f32_16x16x32_bf16(
                    a[m], b[n], acc[m][n], 0, 0, 0);
        __builtin_amdgcn_s_setprio(0);
    };

    bf16x8 fa[8], fb[4];

    // prologue: stage tiles 0,1; confirm tile 0 (all waves) before first read
    stage(0, 0);
    stage(BK, 1);
    VMCNT4;                 // own tile-0 loads done; tile 1 in flight
    BARRIER;                // every wave's tile-0 loads confirmed
    loadfrag(0, fa, fb);

    int bs = 2, br = 1;     // stage buf = (t+2)%3, read buf = (t+1)%3
    for (int t = 0; t < NT; ++t) {
        if (t + 2 < NT) stage((t + 2) * BK, bs);
        if (++bs == 3) bs = 0;
        mfma32(fa, fb);     // consumes loadfrag(t); auto-lgkm drains ds_reads
        if (t + 1 < NT) {
            if (t + 2 < NT) { VMCNT4; } else { VMCNT0; }
            BARRIER;
            loadfrag(br, fa, fb);   // tile t+1
        }
        if (++br == 3) br = 0;
    }

    // ------------------------------------------------------------------
    // Epilogue. C/D frag layout: col = lane&15, row = (lane>>4)*4 + reg.
    // bf16 path: two half-passes via [128][256] ushort LDS tile (64 KB),
    // XOR-swizzled.
    // ------------------------------------------------------------------
    if (OUT_BF16) {
        char* tile = (char*)smem;
        #pragma unroll
        for (int p = 0; p < 2; ++p) {
            __syncthreads();               // prior reads (K-loop / pass) done
            #pragma unroll
            for (int m4 = 0; m4 < 4; ++m4) {
                const int m = p * 4 + m4;
                #pragma unroll
                for (int n = 0; n < 4; ++n) {
                    const int cc = wn * 64 + n * 16 + (lane & 15);
                    const float bv = BIAS ? bias[col0 + cc] : 0.0f;
                    #pragma unroll
                    for (int r = 0; r < 4; ++r) {
                        const int lrow = wm * 64 + m4 * 16 + (lane >> 4) * 4 + r;
                        float v = acc[m][n][r] + bv;
                        if (RELU) v = fmaxf(v, 0.0f);
                        const int byte = (lrow * 512 + cc * 2) ^ (((lrow >> 2) & 3) << 5);
                        *reinterpret_cast<unsigned short*>(tile + byte) = f2bf(v);
                    }
                }
            }
            __syncthreads();
            const int cchunk = tid & 31;        // 16B (8-col) chunk, 32/row
            const int rbase  = tid >> 5;        // 0..15
            #pragma unroll
            for (int it = 0; it < 8; ++it) {
                const int lr = it * 16 + rbase;
                const int byte = (lr * 512 + cchunk * 16) ^ (((lr >> 2) & 3) << 5);
                const uint4 v = *reinterpret_cast<const uint4*>(tile + byte);
                const int grow = row0 + (lr >> 6) * 128 + p * 64 + (lr & 63);
                *reinterpret_cast<uint4*>(
                    &((unsigned short*)Cout)[(size_t)grow * N + col0 + cchunk * 8]) = v;
            }
        }
    } else {
        #pragma unroll
        for (int m = 0; m < 8; ++m) {
            #pragma unroll
            for (int n = 0; n < 4; ++n) {
                const int cg = col0 + wn * 64 + n * 16 + (lane & 15);
                const float bv = BIAS ? bias[cg] : 0.0f;
                #pragma unroll
                for (int r = 0; r < 4; ++r) {
                    const int rg = row0 + wm * 128 + m * 16 + (lane >> 4) * 4 + r;
                    float v = acc[m][n][r] + bv;
                    if (RELU) v = fmaxf(v, 0.0f);
                    ((float*)Cout)[(size_t)rg * N + cg] = v;
                }
            }
        }
    }
}

// ---------------------------------------------------------------------------
// Neighbor attention, one WAVE per (b,t) row; 4 rows per 256-thread block.
// qkv: [M][3072] bf16 (q|k|v). out: [M][1024] bf16.
// Lane l owns channels [l*16, l*16+16). No LDS, no __syncthreads:
// dot-partials butterfly-reduced in-register, idx/radj shfl-broadcast.
// ---------------------------------------------------------------------------
__global__ __launch_bounds__(256) void attn_kernel(
    const unsigned short* __restrict__ qkv, const int* __restrict__ inxs,
    const float* __restrict__ radj, unsigned short* __restrict__ out)
{
    const int wv   = threadIdx.x >> 6;           // 0..3
    const int lane = threadIdx.x & 63;
    const int bt   = blockIdx.x * 4 + wv;
    const int b    = bt >> 10;                   // T = 1024
    const float scale = 0.03125f;                // 1/sqrt(1024)

    // q: 16 channels -> f32 regs
    const unsigned short* qr = &qkv[(size_t)bt * 3072 + lane * 16];
    const bf16x8 q0 = *reinterpret_cast<const bf16x8*>(qr);
    const bf16x8 q1 = *reinterpret_cast<const bf16x8*>(qr + 8);
    float qf[16];
    #pragma unroll
    for (int j = 0; j < 8; ++j) {
        qf[j]     = bf2f((unsigned short)q0[j]);
        qf[j + 8] = bf2f((unsigned short)q1[j]);
    }

    int   iv = 0;
    float rv = 0.f;
    if (lane < K_) {
        iv = inxs[bt * K_ + lane];
        rv = radj[bt * K_ + lane];
    }

    // scores: per-lane partial dots over own 16 channels
    float s[K_];
    #pragma unroll
    for (int k = 0; k < K_; ++k) {
        const int idx = __shfl(iv, k);
        const unsigned short* kr =
            &qkv[((size_t)b * T_ + idx) * 3072 + 1024 + lane * 16];
        const bf16x8 k0 = *reinterpret_cast<const bf16x8*>(kr);
        const bf16x8 k1 = *reinterpret_cast<const bf16x8*>(kr + 8);
        float d = 0.f;
        #pragma unroll
        for (int j = 0; j < 8; ++j) {
            d = fmaf(qf[j],     bf2f((unsigned short)k0[j]), d);
            d = fmaf(qf[j + 8], bf2f((unsigned short)k1[j]), d);
        }
        s[k] = d;
    }
    // full 64-lane butterfly reduce of all 8 partials
    #pragma unroll
    for (int off = 1; off < 64; off <<= 1) {
        #pragma unroll
        for (int k = 0; k < K_; ++k) s[k] += __shfl_xor(s[k], off);
    }

    float sc[K_];
    #pragma unroll
    for (int k = 0; k < K_; ++k) sc[k] = s[k] * scale + __shfl(rv, k);

    // softmax over 8 (redundant per lane)
    float m = sc[0];
    #pragma unroll
    for (int k = 1; k < K_; ++k) m = fmaxf(m, sc[k]);
    float w[K_], wsum = 0.f;
    #pragma unroll
    for (int k = 0; k < K_; ++k) { w[k] = __expf(sc[k] - m); wsum += w[k]; }
    const float inv = 1.0f / wsum;

    // output accumulation over own 16 channels
    float o[16] = {};
    #pragma unroll
    for (int k = 0; k < K_; ++k) {
        const int idx = __shfl(iv, k);
        const unsigned short* vr =
            &qkv[((size_t)b * T_ + idx) * 3072 + 2048 + lane * 16];
        const bf16x8 v0 = *reinterpret_cast<const bf16x8*>(vr);
        const bf16x8 v1 = *reinterpret_cast<const bf16x8*>(vr + 8);
        const float wk = w[k] * inv;
        #pragma unroll
        for (int j = 0; j < 8; ++j) {
            o[j]     = fmaf(wk, bf2f((unsigned short)v0[j]), o[j]);
            o[j + 8] = fmaf(wk, bf2f((unsigned short)v1[j]), o[j + 8]);
        }
    }
    ushort4 pk[2];
    #pragma unroll
    for (int h = 0; h < 2; ++h) {
        pk[h].x = f2bf(o[h * 8 + 0]); pk[h].y = f2bf(o[h * 8 + 1]);
        pk[h].z = f2bf(o[h * 8 + 2]); pk[h].w = f2bf(o[h * 8 + 3]);
    }
    ushort4 pk2[2];
    #pragma unroll
    for (int h = 0; h < 2; ++h) {
        pk2[h].x = f2bf(o[h * 8 + 4]); pk2[h].y = f2bf(o[h * 8 + 5]);
        pk2[h].z = f2bf(o[h * 8 + 6]); pk2[h].w = f2bf(o[h * 8 + 7]);
    }
    unsigned short* op = &out[(size_t)bt * C_ + lane * 16];
    *reinterpret_cast<ushort4*>(op + 0)  = pk[0];
    *reinterpret_cast<ushort4*>(op + 4)  = pk2[0];
    *reinterpret_cast<ushort4*>(op + 8)  = pk[1];
    *reinterpret_cast<ushort4*>(op + 12) = pk2[1];
}

// ---------------------------------------------------------------------------
// out = LayerNorm(a + (RELU ? relu(b) : b)) * g + beta; b is bf16.
// Optional bf16 copy of out.
// ---------------------------------------------------------------------------
template <int RELU, int WB>
__global__ __launch_bounds__(256) void ln_residual_kernel(
    const float* __restrict__ a, const unsigned short* __restrict__ bb,
    const float* __restrict__ g, const float* __restrict__ beta,
    float* __restrict__ out, unsigned short* __restrict__ outb)
{
    const int bt  = blockIdx.x;
    const int tid = threadIdx.x;

    const float4 av = *reinterpret_cast<const float4*>(&a[(size_t)bt * C_ + tid * 4]);
    const ushort4 bu = *reinterpret_cast<const ushort4*>(&bb[(size_t)bt * C_ + tid * 4]);
    float4 bv = make_float4(bf2f(bu.x), bf2f(bu.y), bf2f(bu.z), bf2f(bu.w));
    float4 s;
    s.x = av.x + (RELU ? fmaxf(bv.x, 0.f) : bv.x);
    s.y = av.y + (RELU ? fmaxf(bv.y, 0.f) : bv.y);
    s.z = av.z + (RELU ? fmaxf(bv.z, 0.f) : bv.z);
    s.w = av.w + (RELU ? fmaxf(bv.w, 0.f) : bv.w);

    float sum = s.x + s.y + s.z + s.w;
    float sq  = s.x * s.x + s.y * s.y + s.z * s.z + s.w * s.w;

    const int lane = tid & 63, wid = tid >> 6;
    __shared__ float rs[4], rq[4];
    #pragma unroll
    for (int off = 32; off; off >>= 1) {
        sum += __shfl_xor(sum, off);
        sq  += __shfl_xor(sq,  off);
    }
    if (lane == 0) { rs[wid] = sum; rq[wid] = sq; }
    __syncthreads();
    sum = rs[0] + rs[1] + rs[2] + rs[3];
    sq  = rq[0] + rq[1] + rq[2] + rq[3];

    const float mu  = sum * (1.0f / C_);
    const float var = sq * (1.0f / C_) - mu * mu;
    const float r   = rsqrtf(var + EPS_);

    const float4 gv = *reinterpret_cast<const float4*>(&g[tid * 4]);
    const float4 be = *reinterpret_cast<const float4*>(&beta[tid * 4]);
    float4 o;
    o.x = (s.x - mu) * r * gv.x + be.x;
    o.y = (s.y - mu) * r * gv.y + be.y;
    o.z = (s.z - mu) * r * gv.z + be.z;
    o.w = (s.w - mu) * r * gv.w + be.w;
    *reinterpret_cast<float4*>(&out[(size_t)bt * C_ + tid * 4]) = o;
    if (WB) {
        ushort4 ob;
        ob.x = f2bf(o.x); ob.y = f2bf(o.y); ob.z = f2bf(o.z); ob.w = f2bf(o.w);
        *reinterpret_cast<ushort4*>(&outb[(size_t)bt * C_ + tid * 4]) = ob;
    }
}

// ---------------------------------------------------------------------------
extern "C" void kernel_launch(void* const* d_in, const int* in_sizes, int n_in,
                              void* d_out, int out_size, void* d_ws, size_t ws_size,
                              hipStream_t stream)
{
    const float* x     = (const float*)d_in[0];
    const float* radj  = (const float*)d_in[1];
    const int*   inxs  = (const int*)  d_in[2];
    const float* Wq    = (const float*)d_in[3];
    const float* Wk    = (const float*)d_in[4];
    const float* Wv    = (const float*)d_in[5];
    const float* Wo    = (const float*)d_in[6];
    const float* ln1_g = (const float*)d_in[7];
    const float* ln1_b = (const float*)d_in[8];
    const float* W1    = (const float*)d_in[9];
    const float* b1    = (const float*)d_in[10];
    const float* W2    = (const float*)d_in[11];
    const float* b2    = (const float*)d_in[12];
    const float* ln2_g = (const float*)d_in[13];
    const float* ln2_b = (const float*)d_in[14];
    float* out = (float*)d_out;

    char* wsb = (char*)d_ws;
    const size_t MB = 1 << 20;
    // Weights (bf16, pre-transposed to N x K):
    unsigned short* WqkvT = (unsigned short*)(wsb + 0 * MB);   // 3072x1024, 6 MB
    unsigned short* WoT   = (unsigned short*)(wsb + 6 * MB);   // 1024x1024, 2 MB
    unsigned short* W1T   = (unsigned short*)(wsb + 8 * MB);   // 1536x1024, 3 MB
    unsigned short* W2T   = (unsigned short*)(wsb + 11 * MB);  // 1024x1536, 3 MB
    // Activations (aliased timeline; ws >= 256 MB):
    unsigned short* xb  = (unsigned short*)(wsb + 16 * MB);    // 32 MB; hop state
    unsigned short* hb  = xb;                                  // hop1 Wo out (bf16)
    unsigned short* qkv = (unsigned short*)(wsb + 48 * MB);    // 96 MB (48..144)
    unsigned short* ab  = (unsigned short*)(wsb + 144 * MB);   // 32 MB (144..176)
    unsigned short* h2b = (unsigned short*)(wsb + 48 * MB);    // 32 MB (over dead qkv)
    unsigned short* fb  = (unsigned short*)(wsb + 80 * MB);    // 32 MB (80..112)
    float*          y   = (float*)(wsb + 112 * MB);            // 64 MB (112..176)
    unsigned short* yb  = (unsigned short*)(wsb + 176 * MB);   // 32 MB (176..208)
    unsigned short* hid = (unsigned short*)(wsb + 208 * MB);   // 48 MB (208..256)

    const int M = B_ * T_;
    const dim3 blk(256);
    const dim3 blkG(512);
    const dim3 gQKV(3 * C_ / 256, M / 256);   // 12 x 64 = 768 blocks
    const dim3 gC(C_ / 256, M / 256);         // 4 x 64 = 256
    const dim3 gH(H_ / 256, M / 256);         // 6 x 64 = 384

    // --- weight + input conversion ---
    wtrans_kernel<<<dim3(32, 32), blk, 0, stream>>>(Wq, WqkvT,                C_, C_);
    wtrans_kernel<<<dim3(32, 32), blk, 0, stream>>>(Wk, WqkvT + 1024 * 1024,  C_, C_);
    wtrans_kernel<<<dim3(32, 32), blk, 0, stream>>>(Wv, WqkvT + 2048 * 1024,  C_, C_);
    wtrans_kernel<<<dim3(32, 32), blk, 0, stream>>>(Wo, WoT, C_, C_);
    wtrans_kernel<<<dim3(48, 32), blk, 0, stream>>>(W1, W1T, C_, H_);   // -> H x C
    wtrans_kernel<<<dim3(32, 48), blk, 0, stream>>>(W2, W2T, H_, C_);   // -> C x H
    f2bf_kernel<<<dim3((size_t)M * C_ / 1024), blk, 0, stream>>>(x, xb);

    // --- hops ---
    for (int hop = 0; hop < TNEI_; ++hop) {
        const unsigned short* hin = (hop == 0) ? xb : hb;
        gemm_bt_kernel<1, 0, 0><<<gQKV, blkG, 0, stream>>>(hin, WqkvT, nullptr, qkv,
                                                           M, 3 * C_, C_);
        attn_kernel<<<dim3(M / 4), blk, 0, stream>>>(qkv, inxs, radj, ab);
        if (hop == 0)
            gemm_bt_kernel<1, 0, 0><<<gC, blkG, 0, stream>>>(ab, WoT, nullptr, hb,
                                                             M, C_, C_);
        else
            gemm_bt_kernel<1, 0, 0><<<gC, blkG, 0, stream>>>(ab, WoT, nullptr, h2b,
                                                             M, C_, C_);
    }

    // --- residual + LN1 (f32 y and bf16 yb) ---
    ln_residual_kernel<1, 1><<<dim3(M), blk, 0, stream>>>(x, h2b, ln1_g, ln1_b, y, yb);
    // --- FFN ---
    gemm_bt_kernel<1, 1, 1><<<gH, blkG, 0, stream>>>(yb,  W1T, b1, hid, M, H_, C_);
    gemm_bt_kernel<1, 1, 0><<<gC, blkG, 0, stream>>>(hid, W2T, b2, fb,  M, C_, H_);
    // --- residual + LN2 ---
    ln_residual_kernel<0, 0><<<dim3(M), blk, 0, stream>>>(y, fb, ln2_g, ln2_b, out, nullptr);
}